// Round 4
// baseline (192.130 us; speedup 1.0000x reference)
//
#include <hip/hip_runtime.h>
#include <math.h>

#define NPTS 4096
#define EPSV 1e-5f

// ---------------------------------------------------------------------------
// K1: stage-1 KNN. Points are the flat-view columns P_n = (buf[n], buf[4096+n],
// buf[8192+n]). dist d = 2*p.q - |p|^2 - |q|^2. 64 points x 4 scanners per
// block (chunk=1024: halves wave-level insert-taken rate vs 512), 256-thread
// blocks, 512 blocks = 2 blocks/CU. Register ping-pong prefetch of 8 float4s
// through a per-chunk base pointer (ds_read_b128 with immediate offsets; pts
// padded +8 so no wrap mask). Nested rare-branch insert: common case (new 3rd
// place) is 3 ops. Merge phase uses exact (d desc, idx asc) ordering and only
// needs set-membership from each scanner.
// ---------------------------------------------------------------------------
__global__ __launch_bounds__(256, 2) void k_knn1(const float* __restrict__ x,
                                                 int* __restrict__ idx1) {
  __shared__ float4 pts[NPTS + 8];       // 64.1 KB: x,y,z,|x|^2 (+pad for prefetch)
  __shared__ float cd[64][4][3];         // 3 KB
  __shared__ int   ci[64][4][3];         // 3 KB
  const int b   = blockIdx.x >> 6;       // 64 blocks per batch
  const int blk = blockIdx.x & 63;
  const float* xb = x + b * (NPTS * 3);
  const int t = threadIdx.x;

  for (int m = t; m < NPTS; m += 256) {
    float a0 = xb[m], a1 = xb[NPTS + m], a2 = xb[2 * NPTS + m];
    float xx = a0 * a0; xx = fmaf(a1, a1, xx); xx = fmaf(a2, a2, xx);
    pts[m] = make_float4(a0, a1, a2, xx);
  }
  __syncthreads();

  const int p = t & 63;                  // point within block
  const int s = t >> 6;                  // scanner id (wave-uniform), 0..3
  const int n = blk * 64 + p;
  const float4 pn = pts[n];
  const float p2x = 2.0f * pn.x, p2y = 2.0f * pn.y, p2z = 2.0f * pn.z;
  const float c0 = -pn.w;
  float d0 = -INFINITY, d1 = -INFINITY, d2 = -INFINITY;
  int   i0 = 0x7fffffff, i1 = 0x7fffffff, i2 = 0x7fffffff;
  const int mstart = s * 1024;
  const float4* __restrict__ pchunk = &pts[mstart];

  float4 qa[8];
#pragma unroll
  for (int j = 0; j < 8; ++j) qa[j] = pchunk[j];

  for (int mb = 0; mb < 1024; mb += 16) {
    float4 qb[8];
#pragma unroll
    for (int j = 0; j < 8; ++j) qb[j] = pchunk[mb + 8 + j];
#pragma unroll
    for (int j = 0; j < 8; ++j) {
      float4 q = qa[j];
      float d = fmaf(p2x, q.x, fmaf(p2y, q.y, fmaf(p2z, q.z, c0))) - q.w;
      if (d > d2) {
        int m = mstart + mb + j;
        if (d > d1) {                    // rarer: promote into slot 0/1
          bool g0 = d > d0;
          d2 = d1;            i2 = i1;
          d1 = g0 ? d0 : d;   i1 = g0 ? i0 : m;
          d0 = g0 ? d : d0;   i0 = g0 ? m : i0;
        } else {                         // common: new 3rd place
          d2 = d; i2 = m;
        }
      }
    }
#pragma unroll
    for (int j = 0; j < 8; ++j) qa[j] = pchunk[mb + 16 + j];  // pad keeps in-bounds
#pragma unroll
    for (int j = 0; j < 8; ++j) {
      float4 q = qb[j];
      float d = fmaf(p2x, q.x, fmaf(p2y, q.y, fmaf(p2z, q.z, c0))) - q.w;
      if (d > d2) {
        int m = mstart + mb + 8 + j;
        if (d > d1) {
          bool g0 = d > d0;
          d2 = d1;            i2 = i1;
          d1 = g0 ? d0 : d;   i1 = g0 ? i0 : m;
          d0 = g0 ? d : d0;   i0 = g0 ? m : i0;
        } else {
          d2 = d; i2 = m;
        }
      }
    }
  }

  cd[p][s][0] = d0; cd[p][s][1] = d1; cd[p][s][2] = d2;
  ci[p][s][0] = i0; ci[p][s][1] = i1; ci[p][s][2] = i2;
  __syncthreads();

  if (t < 64) {
    int* op = idx1 + (b * NPTS + blk * 64 + t) * 3;
    float pd = INFINITY; int pi = -1;    // previously selected (none yet)
    for (int r = 0; r < 3; ++r) {
      float bd = -INFINITY; int bi = 0x7fffffff;
      for (int sc = 0; sc < 4; ++sc) {
        for (int kk = 0; kk < 3; ++kk) {
          float dv = cd[t][sc][kk]; int iv = ci[t][sc][kk];
          bool allowed = (dv < pd) || (dv == pd && iv > pi);
          bool better  = (dv > bd) || (dv == bd && iv < bi);
          if (allowed && better) { bd = dv; bi = iv; }
        }
      }
      op[r] = bi;
      pd = bd; pi = bi;
    }
  }
}

// ---------------------------------------------------------------------------
// K2: h[b,o,k,n] = sum_c w1[o,c] * F(c,k,n), partial max over n.
// F(c,k,n): ofs = c*12288 + k*4096 + n ; n'=ofs/18, k'=(ofs%18)/6, c'=ofs%6;
//   c'<3 : x[j*3+c'] - x[n'*3+c'] with j = idx1[n'][k'] ; else x[n'*3+c'-3].
// Gathers go straight to L2 (R3's LDS staging of x cost ~+3.6us -- reverted).
// Grid 8*3*32 blocks (tile = 128 n). Phase B: lane o keeps its w1-row in regs,
// 4 subs x 32 n with ping-pong float4 prefetch; block-reduce subs and write
// pmax transposed: pmax[((b*3+kk)*64+o)*32 + tile].
// ---------------------------------------------------------------------------
__global__ __launch_bounds__(256) void k_convmax(const float* __restrict__ x,
                                                 const int* __restrict__ idx1,
                                                 const float* __restrict__ w1,
                                                 float* __restrict__ pmax) {
  __shared__ float4 Ft4[128][2];         // row: f0..f3 | f4,f5,--,--
  __shared__ float  w1s[384];
  __shared__ float  smax[4][64];
  const int b    = blockIdx.x / 96;      // 96 = 3*32 blocks per batch
  const int rr   = blockIdx.x - b * 96;
  const int kk   = rr >> 5;
  const int tile = rr & 31;
  const int t = threadIdx.x;
  for (int i = t; i < 384; i += 256) w1s[i] = w1[i];
  const float* xb = x + b * 12288;
  const int*   ib = idx1 + b * 12288;

  const int tn = t & 127, ch = t >> 7;   // 2 threads per n, 3 channels each
  const int n = tile * 128 + tn;
  float* ftrow = (float*)&Ft4[tn][0];
#pragma unroll
  for (int j = 0; j < 3; ++j) {
    int c = ch * 3 + j;
    int ofs = c * 12288 + kk * 4096 + n;
    int np  = ofs / 18;
    int rem = ofs - np * 18;
    int kp  = rem / 6;
    int cp  = rem - kp * 6;
    float val;
    if (cp < 3) {
      int jj = ib[np * 3 + kp];
      val = xb[jj * 3 + cp] - xb[np * 3 + cp];
    } else {
      val = xb[np * 3 + cp - 3];
    }
    ftrow[c] = val;
  }
  __syncthreads();

  const int o = t & 63, sub = t >> 6;
  float w[6];
#pragma unroll
  for (int c = 0; c < 6; ++c) w[c] = w1s[o * 6 + c];
  const int base = sub * 32;
  float mx = -INFINITY;

  float4 ra[4][2];
#pragma unroll
  for (int r = 0; r < 4; ++r) { ra[r][0] = Ft4[base + r][0]; ra[r][1] = Ft4[base + r][1]; }

  for (int i = 0; i < 32; i += 8) {
    float4 rb[4][2];
#pragma unroll
    for (int r = 0; r < 4; ++r) {
      rb[r][0] = Ft4[base + i + 4 + r][0];
      rb[r][1] = Ft4[base + i + 4 + r][1];
    }
#pragma unroll
    for (int r = 0; r < 4; ++r) {
      float h = w[0] * ra[r][0].x;
      h = fmaf(w[1], ra[r][0].y, h);
      h = fmaf(w[2], ra[r][0].z, h);
      h = fmaf(w[3], ra[r][0].w, h);
      h = fmaf(w[4], ra[r][1].x, h);
      h = fmaf(w[5], ra[r][1].y, h);
      mx = fmaxf(mx, h);
    }
#pragma unroll
    for (int r = 0; r < 4; ++r) {
      int nr = base + ((i + 8 + r) & 31);
      ra[r][0] = Ft4[nr][0]; ra[r][1] = Ft4[nr][1];
    }
#pragma unroll
    for (int r = 0; r < 4; ++r) {
      float h = w[0] * rb[r][0].x;
      h = fmaf(w[1], rb[r][0].y, h);
      h = fmaf(w[2], rb[r][0].z, h);
      h = fmaf(w[3], rb[r][0].w, h);
      h = fmaf(w[4], rb[r][1].x, h);
      h = fmaf(w[5], rb[r][1].y, h);
      mx = fmaxf(mx, h);
    }
  }
  smax[sub][o] = mx;
  __syncthreads();
  if (t < 64) {
    float m01 = fmaxf(smax[0][t], smax[1][t]);
    float m23 = fmaxf(smax[2][t], smax[3][t]);
    pmax[((b * 3 + kk) * 64 + t) * 32 + tile] = fmaxf(m01, m23);
  }
}

// Stable top-3 insert for the tiny tail stages.
__device__ __forceinline__ void top3_insert(float d, int m,
                                            float& d0, float& d1, float& d2,
                                            int& i0, int& i1, int& i2) {
  if (d > d2) {
    bool g1 = d > d1;
    bool g0 = d > d0;
    d2 = g1 ? d1 : d;                 i2 = g1 ? i1 : m;
    d1 = g0 ? d0 : (g1 ? d : d1);     i1 = g0 ? i0 : (g1 ? m : i1);
    d0 = g0 ? d : d0;                 i0 = g0 ? m : i0;
  }
}

// ---------------------------------------------------------------------------
// K3: per-batch tail. Reduce partials -> bn1+leaky -> x1 (64,3); graph-feature
// stages 2..4 (N=64 then 6,6; same ofs/18 decode); p[82]; MLP A/B/C; softmax.
// ---------------------------------------------------------------------------
__global__ __launch_bounds__(256) void k_tail(
    const float* __restrict__ pmax,
    const float* __restrict__ bn1g, const float* __restrict__ bn1b,
    const float* __restrict__ bn1m, const float* __restrict__ bn1v,
    const float* __restrict__ wA, const float* __restrict__ bA,
    const float* __restrict__ bnAg, const float* __restrict__ bnAb,
    const float* __restrict__ bnAm, const float* __restrict__ bnAv,
    const float* __restrict__ wB, const float* __restrict__ bB,
    const float* __restrict__ bnBg, const float* __restrict__ bnBb,
    const float* __restrict__ bnBm, const float* __restrict__ bnBv,
    const float* __restrict__ wC, const float* __restrict__ bC,
    float* __restrict__ out) {
  __shared__ float a1[192];
  __shared__ int   idx2[192];
  __shared__ float a2[18], a3[18], a4[18];
  __shared__ int   idxs[18];
  __shared__ float pv[82];
  __shared__ float hA[256];
  __shared__ float hB[128];
  __shared__ float lg[3];
  const int b = blockIdx.x;
  const int t = threadIdx.x;

  // step 1: x1[o][k] = leaky(bn1(max over 32 tiles))  (bn monotone: g>0)
  if (t < 192) {
    int o = t / 3, k = t - o * 3;
    const float4* p4 = (const float4*)(pmax + ((b * 3 + k) * 64 + o) * 32);
    float4 v[8];
#pragma unroll
    for (int j = 0; j < 8; ++j) v[j] = p4[j];
    float mx = -INFINITY;
#pragma unroll
    for (int j = 0; j < 8; ++j) {
      mx = fmaxf(mx, fmaxf(fmaxf(v[j].x, v[j].y), fmaxf(v[j].z, v[j].w)));
    }
    float inv = bn1g[o] / sqrtf(bn1v[o] + EPSV);
    float val = (mx - bn1m[o]) * inv + bn1b[o];
    a1[o * 3 + k] = val >= 0.f ? val : 0.2f * val;
  }
  __syncthreads();

  // step 2: KNN over 64 points, P_n = (a1[n], a1[64+n], a1[128+n])
  if (t < 64) {
    float px = a1[t], py = a1[64 + t], pz = a1[128 + t];
    float pp = px * px; pp = fmaf(py, py, pp); pp = fmaf(pz, pz, pp);
    float d0 = -INFINITY, d1 = -INFINITY, d2 = -INFINITY;
    int i0 = 0, i1 = 0, i2 = 0;
#pragma unroll 8
    for (int m = 0; m < 64; ++m) {
      float qx = a1[m], qy = a1[64 + m], qz = a1[128 + m];
      float qq = qx * qx; qq = fmaf(qy, qy, qq); qq = fmaf(qz, qz, qq);
      float dot = px * qx; dot = fmaf(py, qy, dot); dot = fmaf(pz, qz, dot);
      float d = 2.f * dot - pp - qq;
      top3_insert(d, m, d0, d1, d2, i0, i1, i2);
    }
    idx2[t * 3 + 0] = i0; idx2[t * 3 + 1] = i1; idx2[t * 3 + 2] = i2;
  }
  __syncthreads();

  // step 3: x2[o][kk] = max_nn F2(ofs = o*192 + kk*64 + nn)
  if (t < 18) {
    int o = t / 3, kk = t - o * 3;
    float mx = -INFINITY;
#pragma unroll 8
    for (int nn = 0; nn < 64; ++nn) {
      int ofs = o * 192 + kk * 64 + nn;
      int np = ofs / 18; int rem = ofs - np * 18;
      int kp = rem / 6;  int cp  = rem - kp * 6;
      float val = (cp < 3) ? (a1[idx2[np * 3 + kp] * 3 + cp] - a1[np * 3 + cp])
                           : a1[np * 3 + cp - 3];
      mx = fmaxf(mx, val);
    }
    a2[t] = mx;
  }
  __syncthreads();

  // steps 4-5: N=6 graph-feature twice (a2 -> a3 -> a4)
  for (int stage = 0; stage < 2; ++stage) {
    const float* src = (stage == 0) ? a2 : a3;
    float*       dst = (stage == 0) ? a3 : a4;
    if (t < 6) {
      float px = src[t], py = src[6 + t], pz = src[12 + t];
      float pp = px * px; pp = fmaf(py, py, pp); pp = fmaf(pz, pz, pp);
      float d0 = -INFINITY, d1 = -INFINITY, d2 = -INFINITY;
      int i0 = 0, i1 = 0, i2 = 0;
#pragma unroll
      for (int m = 0; m < 6; ++m) {
        float qx = src[m], qy = src[6 + m], qz = src[12 + m];
        float qq = qx * qx; qq = fmaf(qy, qy, qq); qq = fmaf(qz, qz, qq);
        float dot = px * qx; dot = fmaf(py, qy, dot); dot = fmaf(pz, qz, dot);
        float d = 2.f * dot - pp - qq;
        top3_insert(d, m, d0, d1, d2, i0, i1, i2);
      }
      idxs[t * 3 + 0] = i0; idxs[t * 3 + 1] = i1; idxs[t * 3 + 2] = i2;
    }
    __syncthreads();
    if (t < 18) {
      int o = t / 3, kk = t - o * 3;
      float mx = -INFINITY;
#pragma unroll
      for (int nn = 0; nn < 6; ++nn) {
        int ofs = o * 18 + kk * 6 + nn;
        int np = ofs / 18; int rem = ofs - np * 18;
        int kp = rem / 6;  int cp  = rem - kp * 6;
        float val = (cp < 3) ? (src[idxs[np * 3 + kp] * 3 + cp] - src[np * 3 + cp])
                             : src[np * 3 + cp - 3];
        mx = fmaxf(mx, val);
      }
      dst[t] = mx;
    }
    __syncthreads();
  }

  // step 6: p[82] = max over k
  if (t < 82) {
    float mx;
    if (t < 64)      { int o = t;      mx = fmaxf(fmaxf(a1[o*3], a1[o*3+1]), a1[o*3+2]); }
    else if (t < 70) { int o = t - 64; mx = fmaxf(fmaxf(a2[o*3], a2[o*3+1]), a2[o*3+2]); }
    else if (t < 76) { int o = t - 70; mx = fmaxf(fmaxf(a3[o*3], a3[o*3+1]), a3[o*3+2]); }
    else             { int o = t - 76; mx = fmaxf(fmaxf(a4[o*3], a4[o*3+1]), a4[o*3+2]); }
    pv[t] = mx;
  }
  __syncthreads();

  // step 7: hA = leaky(bnA(p @ wA.T + bA))  (256 outputs)
  {
    float acc = bA[t];
    const float* wr = wA + t * 82;
#pragma unroll 8
    for (int i = 0; i < 82; ++i) acc = fmaf(wr[i], pv[i], acc);
    float inv = bnAg[t] / sqrtf(bnAv[t] + EPSV);
    float v = (acc - bnAm[t]) * inv + bnAb[t];
    hA[t] = v >= 0.f ? v : 0.2f * v;
  }
  __syncthreads();

  // step 8: hB (128 outputs)
  if (t < 128) {
    float acc = bB[t];
    const float4* wr4 = (const float4*)(wB + t * 256);
#pragma unroll 8
    for (int i = 0; i < 64; ++i) {
      float4 wv = wr4[i];
      acc = fmaf(wv.x, hA[4 * i + 0], acc);
      acc = fmaf(wv.y, hA[4 * i + 1], acc);
      acc = fmaf(wv.z, hA[4 * i + 2], acc);
      acc = fmaf(wv.w, hA[4 * i + 3], acc);
    }
    float inv = bnBg[t] / sqrtf(bnBv[t] + EPSV);
    float v = (acc - bnBm[t]) * inv + bnBb[t];
    hB[t] = v >= 0.f ? v : 0.2f * v;
  }
  __syncthreads();

  // step 9: logits + softmax
  if (t < 3) {
    float acc = bC[t];
    const float* wr = wC + t * 128;
#pragma unroll 8
    for (int i = 0; i < 128; ++i) acc = fmaf(wr[i], hB[i], acc);
    lg[t] = acc;
  }
  __syncthreads();
  if (t == 0) {
    float m = fmaxf(fmaxf(lg[0], lg[1]), lg[2]);
    float e0 = expf(lg[0] - m), e1 = expf(lg[1] - m), e2 = expf(lg[2] - m);
    float s = e0 + e1 + e2;
    out[b * 3 + 0] = e0 / s;
    out[b * 3 + 1] = e1 / s;
    out[b * 3 + 2] = e2 / s;
  }
}

extern "C" void kernel_launch(void* const* d_in, const int* in_sizes, int n_in,
                              void* d_out, int out_size, void* d_ws, size_t ws_size,
                              hipStream_t stream) {
  (void)in_sizes; (void)n_in; (void)out_size; (void)ws_size;
  const float* x    = (const float*)d_in[0];
  const float* w1   = (const float*)d_in[1];
  const float* wA   = (const float*)d_in[2];
  const float* bA   = (const float*)d_in[3];
  const float* wB   = (const float*)d_in[4];
  const float* bB   = (const float*)d_in[5];
  const float* wC   = (const float*)d_in[6];
  const float* bC   = (const float*)d_in[7];
  const float* bn1g = (const float*)d_in[8];
  const float* bn1b = (const float*)d_in[9];
  const float* bn1m = (const float*)d_in[10];
  const float* bn1v = (const float*)d_in[11];
  const float* bnAg = (const float*)d_in[12];
  const float* bnAb = (const float*)d_in[13];
  const float* bnAm = (const float*)d_in[14];
  const float* bnAv = (const float*)d_in[15];
  const float* bnBg = (const float*)d_in[16];
  const float* bnBb = (const float*)d_in[17];
  const float* bnBm = (const float*)d_in[18];
  const float* bnBv = (const float*)d_in[19];
  float* out = (float*)d_out;

  int*   idx1 = (int*)d_ws;                                  // 8*4096*3 ints = 384 KB
  float* pmax = (float*)((char*)d_ws + 8 * 4096 * 3 * 4);    // 8*3*64*32 floats = 192 KB

  k_knn1<<<512, 256, 0, stream>>>(x, idx1);
  k_convmax<<<768, 256, 0, stream>>>(x, idx1, w1, pmax);
  k_tail<<<8, 256, 0, stream>>>(pmax,
                                bn1g, bn1b, bn1m, bn1v,
                                wA, bA, bnAg, bnAb, bnAm, bnAv,
                                wB, bB, bnBg, bnBb, bnBm, bnBv,
                                wC, bC, out);
}

// Round 5
// 182.687 us; speedup vs baseline: 1.0517x; 1.0517x over previous
//
#include <hip/hip_runtime.h>
#include <math.h>

#define NPTS 4096
#define EPSV 1e-5f

typedef float v2f __attribute__((ext_vector_type(2)));

__device__ __forceinline__ v2f max2(v2f a, v2f b) {
  v2f r; r.x = fmaxf(a.x, b.x); r.y = fmaxf(a.y, b.y); return r;
}

// key(q) = 2p.q - |q|^2  (monotone in -dist^2 for fixed p; per-p shift dropped)
// Contraction (HIP default -ffp-contract=fast) fuses these into fma chains
// identical to the scalar fmaf chain used in the final selection.
__device__ __forceinline__ v2f key2(v2f qx, v2f qy, v2f qz, v2f nw,
                                    v2f p2x, v2f p2y, v2f p2z) {
  return p2x * qx + (p2y * qy + (p2z * qz + nw));
}

// ---------------------------------------------------------------------------
// K1: stage-1 KNN, branchless two-phase.
// Points are flat-view columns P_n = (buf[n], buf[4096+n], buf[8192+n]).
// 64 points x 8 scanners (chunk 512) per 512-thread block; 512 blocks = 2/CU
// (LDS-bound). Phase A: per-scanner chunk-max of key (packed fp32, branchless).
// theta = 3rd-largest of the 8 chunk maxes (provable lower bound on the true
// 3rd-best key). Rescan: collect all k >= theta into LDS candidate list
// (expected ~5 hits/point). Final: exact (key desc, idx asc) top-3 among
// candidates -- matches lax.top_k stable ordering.
// ---------------------------------------------------------------------------
__global__ __launch_bounds__(512, 4) void k_knn1(const float* __restrict__ x,
                                                 int* __restrict__ idx1) {
  __shared__ float qxs[NPTS + 8], qys[NPTS + 8], qzs[NPTS + 8], qws[NPTS + 8];
  __shared__ float scmax[64][8];
  __shared__ float theta[64];
  __shared__ int   ccnt[64];
  __shared__ int   cands[64][24];
  const int b   = blockIdx.x >> 6;       // 64 blocks per batch
  const int blk = blockIdx.x & 63;
  const float* xb = x + b * (NPTS * 3);
  const int t = threadIdx.x;

  for (int m = t; m < NPTS; m += 512) {
    float a0 = xb[m], a1 = xb[NPTS + m], a2 = xb[2 * NPTS + m];
    float w = a0 * a0; w = fmaf(a1, a1, w); w = fmaf(a2, a2, w);
    qxs[m] = a0; qys[m] = a1; qzs[m] = a2; qws[m] = -w;
  }
  if (t < 64) ccnt[t] = 0;
  if (t >= 504) {                        // pad so prefetch stays in-bounds
    int m = NPTS + (t - 504);
    qxs[m] = 0.f; qys[m] = 0.f; qzs[m] = 0.f; qws[m] = -INFINITY;
  }
  __syncthreads();

  const int p = t & 63;                  // point within block
  const int s = t >> 6;                  // scanner id, 0..7 (wave-uniform)
  const int n = blk * 64 + p;
  const float pxv = qxs[n], pyv = qys[n], pzv = qzs[n];
  const v2f p2x = {2.f * pxv, 2.f * pxv};
  const v2f p2y = {2.f * pyv, 2.f * pyv};
  const v2f p2z = {2.f * pzv, 2.f * pzv};
  const int m0 = s * 512;
  const float* bx = &qxs[m0]; const float* by = &qys[m0];
  const float* bz = &qzs[m0]; const float* bw = &qws[m0];

  // ---- phase A: branchless chunk max (ping-pong prefetch of 8 points) ----
  v2f vm = {-INFINITY, -INFINITY};
  float4 ax0 = *(const float4*)&bx[0], ax1 = *(const float4*)&bx[4];
  float4 ay0 = *(const float4*)&by[0], ay1 = *(const float4*)&by[4];
  float4 az0 = *(const float4*)&bz[0], az1 = *(const float4*)&bz[4];
  float4 aw0 = *(const float4*)&bw[0], aw1 = *(const float4*)&bw[4];
  for (int j = 0; j < 512; j += 8) {
    float4 nx0 = *(const float4*)&bx[j + 8], nx1 = *(const float4*)&bx[j + 12];
    float4 ny0 = *(const float4*)&by[j + 8], ny1 = *(const float4*)&by[j + 12];
    float4 nz0 = *(const float4*)&bz[j + 8], nz1 = *(const float4*)&bz[j + 12];
    float4 nw0 = *(const float4*)&bw[j + 8], nw1 = *(const float4*)&bw[j + 12];
    v2f k0 = key2((v2f){ax0.x, ax0.y}, (v2f){ay0.x, ay0.y}, (v2f){az0.x, az0.y}, (v2f){aw0.x, aw0.y}, p2x, p2y, p2z);
    v2f k1 = key2((v2f){ax0.z, ax0.w}, (v2f){ay0.z, ay0.w}, (v2f){az0.z, az0.w}, (v2f){aw0.z, aw0.w}, p2x, p2y, p2z);
    v2f k2 = key2((v2f){ax1.x, ax1.y}, (v2f){ay1.x, ay1.y}, (v2f){az1.x, az1.y}, (v2f){aw1.x, aw1.y}, p2x, p2y, p2z);
    v2f k3 = key2((v2f){ax1.z, ax1.w}, (v2f){ay1.z, ay1.w}, (v2f){az1.z, az1.w}, (v2f){aw1.z, aw1.w}, p2x, p2y, p2z);
    vm = max2(vm, max2(max2(k0, k1), max2(k2, k3)));
    ax0 = nx0; ax1 = nx1; ay0 = ny0; ay1 = ny1;
    az0 = nz0; az1 = nz1; aw0 = nw0; aw1 = nw1;
  }
  scmax[p][s] = fmaxf(vm.x, vm.y);
  __syncthreads();

  // ---- theta[p] = 3rd largest of 8 chunk maxes (values only) ----
  if (t < 64) {
    float d0 = -INFINITY, d1 = -INFINITY, d2 = -INFINITY;
#pragma unroll
    for (int ss = 0; ss < 8; ++ss) {
      float v = scmax[t][ss];
      float nd2 = fmaxf(d2, fminf(d1, v));
      float nd1 = fmaxf(d1, fminf(d0, v));
      d0 = fmaxf(d0, v); d1 = nd1; d2 = nd2;
    }
    theta[t] = d2;
  }
  __syncthreads();
  const float th = theta[p];

  // ---- rescan: collect candidates with key >= theta ----
  ax0 = *(const float4*)&bx[0]; ax1 = *(const float4*)&bx[4];
  ay0 = *(const float4*)&by[0]; ay1 = *(const float4*)&by[4];
  az0 = *(const float4*)&bz[0]; az1 = *(const float4*)&bz[4];
  aw0 = *(const float4*)&bw[0]; aw1 = *(const float4*)&bw[4];
  for (int j = 0; j < 512; j += 8) {
    float4 nx0 = *(const float4*)&bx[j + 8], nx1 = *(const float4*)&bx[j + 12];
    float4 ny0 = *(const float4*)&by[j + 8], ny1 = *(const float4*)&by[j + 12];
    float4 nz0 = *(const float4*)&bz[j + 8], nz1 = *(const float4*)&bz[j + 12];
    float4 nw0 = *(const float4*)&bw[j + 8], nw1 = *(const float4*)&bw[j + 12];
    v2f k0 = key2((v2f){ax0.x, ax0.y}, (v2f){ay0.x, ay0.y}, (v2f){az0.x, az0.y}, (v2f){aw0.x, aw0.y}, p2x, p2y, p2z);
    v2f k1 = key2((v2f){ax0.z, ax0.w}, (v2f){ay0.z, ay0.w}, (v2f){az0.z, az0.w}, (v2f){aw0.z, aw0.w}, p2x, p2y, p2z);
    v2f k2 = key2((v2f){ax1.x, ax1.y}, (v2f){ay1.x, ay1.y}, (v2f){az1.x, az1.y}, (v2f){aw1.x, aw1.y}, p2x, p2y, p2z);
    v2f k3 = key2((v2f){ax1.z, ax1.w}, (v2f){ay1.z, ay1.w}, (v2f){az1.z, az1.w}, (v2f){aw1.z, aw1.w}, p2x, p2y, p2z);
    v2f mc = max2(max2(k0, k1), max2(k2, k3));
    float mm = fmaxf(mc.x, mc.y);
    if (mm >= th) {                      // rare: ~5 hits per point per 4096
      float kk[8] = {k0.x, k0.y, k1.x, k1.y, k2.x, k2.y, k3.x, k3.y};
#pragma unroll
      for (int u = 0; u < 8; ++u) {
        if (kk[u] >= th) {
          int c = atomicAdd(&ccnt[p], 1);
          if (c < 24) cands[p][c] = m0 + j + u;
        }
      }
    }
    ax0 = nx0; ax1 = nx1; ay0 = ny0; ay1 = ny1;
    az0 = nz0; az1 = nz1; aw0 = nw0; aw1 = nw1;
  }
  __syncthreads();

  // ---- final: exact (key desc, idx asc) top-3 among candidates ----
  if (t < 64) {
    int cnt = ccnt[t]; if (cnt > 24) cnt = 24;
    const int nn = blk * 64 + t;
    const float P2X = 2.f * qxs[nn], P2Y = 2.f * qys[nn], P2Z = 2.f * qzs[nn];
    int* op = idx1 + (b * NPTS + nn) * 3;
    float pd = INFINITY; int pi = -1;
    for (int r = 0; r < 3; ++r) {
      float bd = -INFINITY; int bi = 0x7fffffff;
      for (int c = 0; c < cnt; ++c) {
        int m = cands[t][c];
        float kv = fmaf(P2X, qxs[m], fmaf(P2Y, qys[m], fmaf(P2Z, qzs[m], qws[m])));
        bool allowed = (kv < pd) || (kv == pd && m > pi);
        bool better  = (kv > bd) || (kv == bd && m < bi);
        if (allowed && better) { bd = kv; bi = m; }
      }
      op[r] = bi;
      pd = bd; pi = bi;
    }
  }
}

// ---------------------------------------------------------------------------
// K2: h[b,o,k,n] = sum_c w1[o,c] * F(c,k,n), partial max over n.
// F(c,k,n): ofs = c*12288 + k*4096 + n ; n'=ofs/18, k'=(ofs%18)/6, c'=ofs%6;
//   c'<3 : x[j*3+c'] - x[n'*3+c'] with j = idx1[n'][k'] ; else x[n'*3+c'-3].
// Gathers go straight to L2 (LDS staging of x cost +3.6us in R3 -- reverted).
// Grid 8*3*32 blocks (tile = 128 n); write pmax transposed for the tail.
// ---------------------------------------------------------------------------
__global__ __launch_bounds__(256) void k_convmax(const float* __restrict__ x,
                                                 const int* __restrict__ idx1,
                                                 const float* __restrict__ w1,
                                                 float* __restrict__ pmax) {
  __shared__ float4 Ft4[128][2];         // row: f0..f3 | f4,f5,--,--
  __shared__ float  w1s[384];
  __shared__ float  smax[4][64];
  const int b    = blockIdx.x / 96;      // 96 = 3*32 blocks per batch
  const int rr   = blockIdx.x - b * 96;
  const int kk   = rr >> 5;
  const int tile = rr & 31;
  const int t = threadIdx.x;
  for (int i = t; i < 384; i += 256) w1s[i] = w1[i];
  const float* xb = x + b * 12288;
  const int*   ib = idx1 + b * 12288;

  const int tn = t & 127, ch = t >> 7;   // 2 threads per n, 3 channels each
  const int n = tile * 128 + tn;
  float* ftrow = (float*)&Ft4[tn][0];
#pragma unroll
  for (int j = 0; j < 3; ++j) {
    int c = ch * 3 + j;
    int ofs = c * 12288 + kk * 4096 + n;
    int np  = ofs / 18;
    int rem = ofs - np * 18;
    int kp  = rem / 6;
    int cp  = rem - kp * 6;
    float val;
    if (cp < 3) {
      int jj = ib[np * 3 + kp];
      val = xb[jj * 3 + cp] - xb[np * 3 + cp];
    } else {
      val = xb[np * 3 + cp - 3];
    }
    ftrow[c] = val;
  }
  __syncthreads();

  const int o = t & 63, sub = t >> 6;
  float w[6];
#pragma unroll
  for (int c = 0; c < 6; ++c) w[c] = w1s[o * 6 + c];
  const int base = sub * 32;
  float mx = -INFINITY;

  float4 ra[4][2];
#pragma unroll
  for (int r = 0; r < 4; ++r) { ra[r][0] = Ft4[base + r][0]; ra[r][1] = Ft4[base + r][1]; }

  for (int i = 0; i < 32; i += 8) {
    float4 rb[4][2];
#pragma unroll
    for (int r = 0; r < 4; ++r) {
      rb[r][0] = Ft4[base + i + 4 + r][0];
      rb[r][1] = Ft4[base + i + 4 + r][1];
    }
#pragma unroll
    for (int r = 0; r < 4; ++r) {
      float h = w[0] * ra[r][0].x;
      h = fmaf(w[1], ra[r][0].y, h);
      h = fmaf(w[2], ra[r][0].z, h);
      h = fmaf(w[3], ra[r][0].w, h);
      h = fmaf(w[4], ra[r][1].x, h);
      h = fmaf(w[5], ra[r][1].y, h);
      mx = fmaxf(mx, h);
    }
#pragma unroll
    for (int r = 0; r < 4; ++r) {
      int nr = base + ((i + 8 + r) & 31);
      ra[r][0] = Ft4[nr][0]; ra[r][1] = Ft4[nr][1];
    }
#pragma unroll
    for (int r = 0; r < 4; ++r) {
      float h = w[0] * rb[r][0].x;
      h = fmaf(w[1], rb[r][0].y, h);
      h = fmaf(w[2], rb[r][0].z, h);
      h = fmaf(w[3], rb[r][0].w, h);
      h = fmaf(w[4], rb[r][1].x, h);
      h = fmaf(w[5], rb[r][1].y, h);
      mx = fmaxf(mx, h);
    }
  }
  smax[sub][o] = mx;
  __syncthreads();
  if (t < 64) {
    float m01 = fmaxf(smax[0][t], smax[1][t]);
    float m23 = fmaxf(smax[2][t], smax[3][t]);
    pmax[((b * 3 + kk) * 64 + t) * 32 + tile] = fmaxf(m01, m23);
  }
}

// Stable top-3 insert for the tiny tail stages.
__device__ __forceinline__ void top3_insert(float d, int m,
                                            float& d0, float& d1, float& d2,
                                            int& i0, int& i1, int& i2) {
  if (d > d2) {
    bool g1 = d > d1;
    bool g0 = d > d0;
    d2 = g1 ? d1 : d;                 i2 = g1 ? i1 : m;
    d1 = g0 ? d0 : (g1 ? d : d1);     i1 = g0 ? i0 : (g1 ? m : i1);
    d0 = g0 ? d : d0;                 i0 = g0 ? m : i0;
  }
}

// ---------------------------------------------------------------------------
// K3: per-batch tail. Reduce partials -> bn1+leaky -> x1 (64,3); graph-feature
// stages 2..4 (N=64 then 6,6; same ofs/18 decode); p[82]; MLP A/B/C; softmax.
// ---------------------------------------------------------------------------
__global__ __launch_bounds__(256) void k_tail(
    const float* __restrict__ pmax,
    const float* __restrict__ bn1g, const float* __restrict__ bn1b,
    const float* __restrict__ bn1m, const float* __restrict__ bn1v,
    const float* __restrict__ wA, const float* __restrict__ bA,
    const float* __restrict__ bnAg, const float* __restrict__ bnAb,
    const float* __restrict__ bnAm, const float* __restrict__ bnAv,
    const float* __restrict__ wB, const float* __restrict__ bB,
    const float* __restrict__ bnBg, const float* __restrict__ bnBb,
    const float* __restrict__ bnBm, const float* __restrict__ bnBv,
    const float* __restrict__ wC, const float* __restrict__ bC,
    float* __restrict__ out) {
  __shared__ float a1[192];
  __shared__ int   idx2[192];
  __shared__ float a2[18], a3[18], a4[18];
  __shared__ int   idxs[18];
  __shared__ float pv[82];
  __shared__ float hA[256];
  __shared__ float hB[128];
  __shared__ float lg[3];
  const int b = blockIdx.x;
  const int t = threadIdx.x;

  // step 1: x1[o][k] = leaky(bn1(max over 32 tiles))  (bn monotone: g>0)
  if (t < 192) {
    int o = t / 3, k = t - o * 3;
    const float4* p4 = (const float4*)(pmax + ((b * 3 + k) * 64 + o) * 32);
    float4 v[8];
#pragma unroll
    for (int j = 0; j < 8; ++j) v[j] = p4[j];
    float mx = -INFINITY;
#pragma unroll
    for (int j = 0; j < 8; ++j) {
      mx = fmaxf(mx, fmaxf(fmaxf(v[j].x, v[j].y), fmaxf(v[j].z, v[j].w)));
    }
    float inv = bn1g[o] / sqrtf(bn1v[o] + EPSV);
    float val = (mx - bn1m[o]) * inv + bn1b[o];
    a1[o * 3 + k] = val >= 0.f ? val : 0.2f * val;
  }
  __syncthreads();

  // step 2: KNN over 64 points, P_n = (a1[n], a1[64+n], a1[128+n])
  if (t < 64) {
    float px = a1[t], py = a1[64 + t], pz = a1[128 + t];
    float pp = px * px; pp = fmaf(py, py, pp); pp = fmaf(pz, pz, pp);
    float d0 = -INFINITY, d1 = -INFINITY, d2 = -INFINITY;
    int i0 = 0, i1 = 0, i2 = 0;
#pragma unroll 8
    for (int m = 0; m < 64; ++m) {
      float qx = a1[m], qy = a1[64 + m], qz = a1[128 + m];
      float qq = qx * qx; qq = fmaf(qy, qy, qq); qq = fmaf(qz, qz, qq);
      float dot = px * qx; dot = fmaf(py, qy, dot); dot = fmaf(pz, qz, dot);
      float d = 2.f * dot - pp - qq;
      top3_insert(d, m, d0, d1, d2, i0, i1, i2);
    }
    idx2[t * 3 + 0] = i0; idx2[t * 3 + 1] = i1; idx2[t * 3 + 2] = i2;
  }
  __syncthreads();

  // step 3: x2[o][kk] = max_nn F2(ofs = o*192 + kk*64 + nn)
  if (t < 18) {
    int o = t / 3, kk = t - o * 3;
    float mx = -INFINITY;
#pragma unroll 8
    for (int nn = 0; nn < 64; ++nn) {
      int ofs = o * 192 + kk * 64 + nn;
      int np = ofs / 18; int rem = ofs - np * 18;
      int kp = rem / 6;  int cp  = rem - kp * 6;
      float val = (cp < 3) ? (a1[idx2[np * 3 + kp] * 3 + cp] - a1[np * 3 + cp])
                           : a1[np * 3 + cp - 3];
      mx = fmaxf(mx, val);
    }
    a2[t] = mx;
  }
  __syncthreads();

  // steps 4-5: N=6 graph-feature twice (a2 -> a3 -> a4)
  for (int stage = 0; stage < 2; ++stage) {
    const float* src = (stage == 0) ? a2 : a3;
    float*       dst = (stage == 0) ? a3 : a4;
    if (t < 6) {
      float px = src[t], py = src[6 + t], pz = src[12 + t];
      float pp = px * px; pp = fmaf(py, py, pp); pp = fmaf(pz, pz, pp);
      float d0 = -INFINITY, d1 = -INFINITY, d2 = -INFINITY;
      int i0 = 0, i1 = 0, i2 = 0;
#pragma unroll
      for (int m = 0; m < 6; ++m) {
        float qx = src[m], qy = src[6 + m], qz = src[12 + m];
        float qq = qx * qx; qq = fmaf(qy, qy, qq); qq = fmaf(qz, qz, qq);
        float dot = px * qx; dot = fmaf(py, qy, dot); dot = fmaf(pz, qz, dot);
        float d = 2.f * dot - pp - qq;
        top3_insert(d, m, d0, d1, d2, i0, i1, i2);
      }
      idxs[t * 3 + 0] = i0; idxs[t * 3 + 1] = i1; idxs[t * 3 + 2] = i2;
    }
    __syncthreads();
    if (t < 18) {
      int o = t / 3, kk = t - o * 3;
      float mx = -INFINITY;
#pragma unroll
      for (int nn = 0; nn < 6; ++nn) {
        int ofs = o * 18 + kk * 6 + nn;
        int np = ofs / 18; int rem = ofs - np * 18;
        int kp = rem / 6;  int cp  = rem - kp * 6;
        float val = (cp < 3) ? (src[idxs[np * 3 + kp] * 3 + cp] - src[np * 3 + cp])
                             : src[np * 3 + cp - 3];
        mx = fmaxf(mx, val);
      }
      dst[t] = mx;
    }
    __syncthreads();
  }

  // step 6: p[82] = max over k
  if (t < 82) {
    float mx;
    if (t < 64)      { int o = t;      mx = fmaxf(fmaxf(a1[o*3], a1[o*3+1]), a1[o*3+2]); }
    else if (t < 70) { int o = t - 64; mx = fmaxf(fmaxf(a2[o*3], a2[o*3+1]), a2[o*3+2]); }
    else if (t < 76) { int o = t - 70; mx = fmaxf(fmaxf(a3[o*3], a3[o*3+1]), a3[o*3+2]); }
    else             { int o = t - 76; mx = fmaxf(fmaxf(a4[o*3], a4[o*3+1]), a4[o*3+2]); }
    pv[t] = mx;
  }
  __syncthreads();

  // step 7: hA = leaky(bnA(p @ wA.T + bA))  (256 outputs)
  {
    float acc = bA[t];
    const float* wr = wA + t * 82;
#pragma unroll 8
    for (int i = 0; i < 82; ++i) acc = fmaf(wr[i], pv[i], acc);
    float inv = bnAg[t] / sqrtf(bnAv[t] + EPSV);
    float v = (acc - bnAm[t]) * inv + bnAb[t];
    hA[t] = v >= 0.f ? v : 0.2f * v;
  }
  __syncthreads();

  // step 8: hB (128 outputs)
  if (t < 128) {
    float acc = bB[t];
    const float4* wr4 = (const float4*)(wB + t * 256);
#pragma unroll 8
    for (int i = 0; i < 64; ++i) {
      float4 wv = wr4[i];
      acc = fmaf(wv.x, hA[4 * i + 0], acc);
      acc = fmaf(wv.y, hA[4 * i + 1], acc);
      acc = fmaf(wv.z, hA[4 * i + 2], acc);
      acc = fmaf(wv.w, hA[4 * i + 3], acc);
    }
    float inv = bnBg[t] / sqrtf(bnBv[t] + EPSV);
    float v = (acc - bnBm[t]) * inv + bnBb[t];
    hB[t] = v >= 0.f ? v : 0.2f * v;
  }
  __syncthreads();

  // step 9: logits + softmax
  if (t < 3) {
    float acc = bC[t];
    const float* wr = wC + t * 128;
#pragma unroll 8
    for (int i = 0; i < 128; ++i) acc = fmaf(wr[i], hB[i], acc);
    lg[t] = acc;
  }
  __syncthreads();
  if (t == 0) {
    float m = fmaxf(fmaxf(lg[0], lg[1]), lg[2]);
    float e0 = expf(lg[0] - m), e1 = expf(lg[1] - m), e2 = expf(lg[2] - m);
    float s = e0 + e1 + e2;
    out[b * 3 + 0] = e0 / s;
    out[b * 3 + 1] = e1 / s;
    out[b * 3 + 2] = e2 / s;
  }
}

extern "C" void kernel_launch(void* const* d_in, const int* in_sizes, int n_in,
                              void* d_out, int out_size, void* d_ws, size_t ws_size,
                              hipStream_t stream) {
  (void)in_sizes; (void)n_in; (void)out_size; (void)ws_size;
  const float* x    = (const float*)d_in[0];
  const float* w1   = (const float*)d_in[1];
  const float* wA   = (const float*)d_in[2];
  const float* bA   = (const float*)d_in[3];
  const float* wB   = (const float*)d_in[4];
  const float* bB   = (const float*)d_in[5];
  const float* wC   = (const float*)d_in[6];
  const float* bC   = (const float*)d_in[7];
  const float* bn1g = (const float*)d_in[8];
  const float* bn1b = (const float*)d_in[9];
  const float* bn1m = (const float*)d_in[10];
  const float* bn1v = (const float*)d_in[11];
  const float* bnAg = (const float*)d_in[12];
  const float* bnAb = (const float*)d_in[13];
  const float* bnAm = (const float*)d_in[14];
  const float* bnAv = (const float*)d_in[15];
  const float* bnBg = (const float*)d_in[16];
  const float* bnBb = (const float*)d_in[17];
  const float* bnBm = (const float*)d_in[18];
  const float* bnBv = (const float*)d_in[19];
  float* out = (float*)d_out;

  int*   idx1 = (int*)d_ws;                                  // 8*4096*3 ints = 384 KB
  float* pmax = (float*)((char*)d_ws + 8 * 4096 * 3 * 4);    // 8*3*64*32 floats = 192 KB

  k_knn1<<<512, 512, 0, stream>>>(x, idx1);
  k_convmax<<<768, 256, 0, stream>>>(x, idx1, w1, pmax);
  k_tail<<<8, 256, 0, stream>>>(pmax,
                                bn1g, bn1b, bn1m, bn1v,
                                wA, bA, bnAg, bnAb, bnAm, bnAv,
                                wB, bB, bnBg, bnBb, bnBm, bnBv,
                                wC, bC, out);
}

// Round 6
// 177.872 us; speedup vs baseline: 1.0802x; 1.0271x over previous
//
#include <hip/hip_runtime.h>
#include <math.h>

#define NPTS 4096
#define EPSV 1e-5f

// 16-lane xor-butterfly max via DPP (VALU-rate, no LDS pipe).
// Generators xor1 (quad_perm[1,0,3,2]=0xB1), xor2 (quad_perm[2,3,0,1]=0x4E),
// xor7 (ROW_HALF_MIRROR=0x141), xor15 (ROW_MIRROR=0x140).
template <int CTRL>
__device__ __forceinline__ float dpp_max(float v) {
#if __has_builtin(__builtin_amdgcn_update_dpp)
  int o = __builtin_amdgcn_update_dpp(0, __float_as_int(v), CTRL, 0xF, 0xF, true);
  return fmaxf(v, __int_as_float(o));
#else
  int lanemask = (CTRL == 0xB1) ? 1 : (CTRL == 0x4E) ? 2 : (CTRL == 0x141) ? 7 : 15;
  return fmaxf(v, __shfl_xor(v, lanemask, 16));
#endif
}

// ---------------------------------------------------------------------------
// K1: stage-1 KNN, m-in-registers two-phase.
// Points are flat-view columns P_n = (buf[n], buf[4096+n], buf[8192+n]).
// key(q) = 2p.q - |q|^2 (per-p constant shift dropped; order-preserving).
// Block: 512 threads, thread t owns m in [8t,8t+8) in VGPRs; 16-lane group
// g covers 128 m. Covers 64 p's (grid 8b x 64 pranges = 512 blocks, 2/CU).
// Phase A: per-(p,group) max via reg-local 8-max + 4 DPP steps -> scmax.
// theta[p] = 3rd-largest of 32 group maxes (<= true 3rd key: 3 distinct
// key instances from 3 groups). Rescan: only hit groups (~3/32) recompute
// keys from regs, append m with key >= theta to cands (LDS atomics).
// Final: exact (key desc, idx asc) top-3 among <=24 cands = lax.top_k stable.
// ---------------------------------------------------------------------------
__global__ __launch_bounds__(512, 4) void k_knn1(const float* __restrict__ x,
                                                 int* __restrict__ idx1) {
  __shared__ float qxs[NPTS], qys[NPTS], qzs[NPTS];   // 48 KB SoA
  __shared__ float4 ppre[68];                         // (2px,2py,2pz,0) +pad
  __shared__ float scmax[65][32];                     // +1 row pad for prefetch
  __shared__ float theta[65];
  __shared__ int   cnt[64];
  __shared__ int   cands[64][24];
  const int b     = blockIdx.x >> 6;     // 64 p-ranges per batch
  const int pr    = blockIdx.x & 63;
  const int pbase = pr * 64;
  const float* xb = x + b * (NPTS * 3);
  const int t = threadIdx.x;
  const int g = t >> 4;                  // group 0..31 (128 m each)

  // ---- stage: coalesced global loads; regs + LDS SoA copies ----
  float qx[8], qy[8], qz[8], qw[8];
  {
    const float4* X = (const float4*)(xb + 8 * t);
    const float4* Y = (const float4*)(xb + NPTS + 8 * t);
    const float4* Z = (const float4*)(xb + 2 * NPTS + 8 * t);
    float4 x0 = X[0], x1 = X[1];
    float4 y0 = Y[0], y1 = Y[1];
    float4 z0 = Z[0], z1 = Z[1];
    qx[0] = x0.x; qx[1] = x0.y; qx[2] = x0.z; qx[3] = x0.w;
    qx[4] = x1.x; qx[5] = x1.y; qx[6] = x1.z; qx[7] = x1.w;
    qy[0] = y0.x; qy[1] = y0.y; qy[2] = y0.z; qy[3] = y0.w;
    qy[4] = y1.x; qy[5] = y1.y; qy[6] = y1.z; qy[7] = y1.w;
    qz[0] = z0.x; qz[1] = z0.y; qz[2] = z0.z; qz[3] = z0.w;
    qz[4] = z1.x; qz[5] = z1.y; qz[6] = z1.z; qz[7] = z1.w;
    *(float4*)&qxs[8 * t] = x0; *(float4*)&qxs[8 * t + 4] = x1;
    *(float4*)&qys[8 * t] = y0; *(float4*)&qys[8 * t + 4] = y1;
    *(float4*)&qzs[8 * t] = z0; *(float4*)&qzs[8 * t + 4] = z1;
  }
#pragma unroll
  for (int j = 0; j < 8; ++j)
    qw[j] = -fmaf(qz[j], qz[j], fmaf(qy[j], qy[j], qx[j] * qx[j]));
  if (t < 64) cnt[t] = 0;
  __syncthreads();
  if (t < 64) {
    float px = qxs[pbase + t], py = qys[pbase + t], pz = qzs[pbase + t];
    ppre[t] = make_float4(2.f * px, 2.f * py, 2.f * pz, 0.f);
  } else if (t < 68) {
    ppre[t] = make_float4(0.f, 0.f, 0.f, 0.f);
  }
  __syncthreads();

  // ---- phase A: per-(p,group) max ----
  auto proc = [&](float4 P, int p) {
    float k0 = fmaf(P.x, qx[0], fmaf(P.y, qy[0], fmaf(P.z, qz[0], qw[0])));
    float k1 = fmaf(P.x, qx[1], fmaf(P.y, qy[1], fmaf(P.z, qz[1], qw[1])));
    float k2 = fmaf(P.x, qx[2], fmaf(P.y, qy[2], fmaf(P.z, qz[2], qw[2])));
    float k3 = fmaf(P.x, qx[3], fmaf(P.y, qy[3], fmaf(P.z, qz[3], qw[3])));
    float k4 = fmaf(P.x, qx[4], fmaf(P.y, qy[4], fmaf(P.z, qz[4], qw[4])));
    float k5 = fmaf(P.x, qx[5], fmaf(P.y, qy[5], fmaf(P.z, qz[5], qw[5])));
    float k6 = fmaf(P.x, qx[6], fmaf(P.y, qy[6], fmaf(P.z, qz[6], qw[6])));
    float k7 = fmaf(P.x, qx[7], fmaf(P.y, qy[7], fmaf(P.z, qz[7], qw[7])));
    float v = fmaxf(fmaxf(fmaxf(k0, k1), fmaxf(k2, k3)),
                    fmaxf(fmaxf(k4, k5), fmaxf(k6, k7)));
    v = dpp_max<0xB1>(v);               // xor1
    v = dpp_max<0x4E>(v);               // xor2
    v = dpp_max<0x141>(v);              // xor7  (row_half_mirror)
    v = dpp_max<0x140>(v);              // xor15 (row_mirror)
    if ((t & 15) == 0) scmax[p][g] = v;
  };
  {
    float4 pp0 = ppre[0], pp1 = ppre[1], pp2 = ppre[2], pp3 = ppre[3];
    for (int p0 = 0; p0 < 64; p0 += 4) {
      float4 n0 = ppre[p0 + 4], n1 = ppre[p0 + 5];
      float4 n2 = ppre[p0 + 6], n3 = ppre[p0 + 7];
      proc(pp0, p0 + 0); proc(pp1, p0 + 1);
      proc(pp2, p0 + 2); proc(pp3, p0 + 3);
      pp0 = n0; pp1 = n1; pp2 = n2; pp3 = n3;
    }
  }
  __syncthreads();

  // ---- theta[p] = 3rd-largest of 32 group maxes ----
  if (t < 64) {
    const float4* row = (const float4*)scmax[t];
    float d0 = -INFINITY, d1 = -INFINITY, d2 = -INFINITY;
#pragma unroll
    for (int q4 = 0; q4 < 8; ++q4) {
      float4 vv = row[q4];
      float va[4] = {vv.x, vv.y, vv.z, vv.w};
#pragma unroll
      for (int u = 0; u < 4; ++u) {
        float v = va[u];
        float nd2 = fmaxf(d2, fminf(d1, v));
        float nd1 = fmaxf(d1, fminf(d0, v));
        d0 = fmaxf(d0, v); d1 = nd1; d2 = nd2;
      }
    }
    theta[t] = d2;
  }
  __syncthreads();

  // ---- rescan: hit groups only (~3/32 per p) ----
  {
    float gm = scmax[0][g], th = theta[0];
    for (int p = 0; p < 64; ++p) {
      float ngm = scmax[p + 1][g];      // row 64 is pad; value unused
      float nth = theta[p + 1];
      if (gm >= th) {
        float4 P = ppre[p];
#pragma unroll
        for (int j = 0; j < 8; ++j) {
          float kj = fmaf(P.x, qx[j], fmaf(P.y, qy[j], fmaf(P.z, qz[j], qw[j])));
          if (kj >= th) {
            int c = atomicAdd(&cnt[p], 1);
            if (c < 24) cands[p][c] = 8 * t + j;
          }
        }
      }
      gm = ngm; th = nth;
    }
  }
  __syncthreads();

  // ---- final: exact (key desc, idx asc) top-3 among candidates ----
  if (t < 64) {
    int c = cnt[t]; if (c > 24) c = 24;
    const float4 P = ppre[t];
    int* op = idx1 + (b * NPTS + pbase + t) * 3;
    float pd = INFINITY; int pi = -1;
    for (int r = 0; r < 3; ++r) {
      float bd = -INFINITY; int bi = 0x7fffffff;
      for (int cc = 0; cc < c; ++cc) {
        int m = cands[t][cc];
        float mxv = qxs[m], myv = qys[m], mzv = qzs[m];
        float mw = -fmaf(mzv, mzv, fmaf(myv, myv, mxv * mxv));
        float kv = fmaf(P.x, mxv, fmaf(P.y, myv, fmaf(P.z, mzv, mw)));
        bool allowed = (kv < pd) || (kv == pd && m > pi);
        bool better  = (kv > bd) || (kv == bd && m < bi);
        if (allowed && better) { bd = kv; bi = m; }
      }
      op[r] = bi;
      pd = bd; pi = bi;
    }
  }
}

// ---------------------------------------------------------------------------
// K2: h[b,o,k,n] = sum_c w1[o,c] * F(c,k,n), partial max over n.
// F(c,k,n): ofs = c*12288 + k*4096 + n ; n'=ofs/18, k'=(ofs%18)/6, c'=ofs%6;
//   c'<3 : x[j*3+c'] - x[n'*3+c'] with j = idx1[n'][k'] ; else x[n'*3+c'-3].
// Gathers go straight to L2 (LDS staging of x cost +3.6us in R3 -- reverted).
// Grid 8*3*32 blocks (tile = 128 n); write pmax transposed for the tail.
// ---------------------------------------------------------------------------
__global__ __launch_bounds__(256) void k_convmax(const float* __restrict__ x,
                                                 const int* __restrict__ idx1,
                                                 const float* __restrict__ w1,
                                                 float* __restrict__ pmax) {
  __shared__ float4 Ft4[128][2];         // row: f0..f3 | f4,f5,--,--
  __shared__ float  w1s[384];
  __shared__ float  smax[4][64];
  const int b    = blockIdx.x / 96;      // 96 = 3*32 blocks per batch
  const int rr   = blockIdx.x - b * 96;
  const int kk   = rr >> 5;
  const int tile = rr & 31;
  const int t = threadIdx.x;
  for (int i = t; i < 384; i += 256) w1s[i] = w1[i];
  const float* xb = x + b * 12288;
  const int*   ib = idx1 + b * 12288;

  const int tn = t & 127, ch = t >> 7;   // 2 threads per n, 3 channels each
  const int n = tile * 128 + tn;
  float* ftrow = (float*)&Ft4[tn][0];
#pragma unroll
  for (int j = 0; j < 3; ++j) {
    int c = ch * 3 + j;
    int ofs = c * 12288 + kk * 4096 + n;
    int np  = ofs / 18;
    int rem = ofs - np * 18;
    int kp  = rem / 6;
    int cp  = rem - kp * 6;
    float val;
    if (cp < 3) {
      int jj = ib[np * 3 + kp];
      val = xb[jj * 3 + cp] - xb[np * 3 + cp];
    } else {
      val = xb[np * 3 + cp - 3];
    }
    ftrow[c] = val;
  }
  __syncthreads();

  const int o = t & 63, sub = t >> 6;
  float w[6];
#pragma unroll
  for (int c = 0; c < 6; ++c) w[c] = w1s[o * 6 + c];
  const int base = sub * 32;
  float mx = -INFINITY;

  float4 ra[4][2];
#pragma unroll
  for (int r = 0; r < 4; ++r) { ra[r][0] = Ft4[base + r][0]; ra[r][1] = Ft4[base + r][1]; }

  for (int i = 0; i < 32; i += 8) {
    float4 rb[4][2];
#pragma unroll
    for (int r = 0; r < 4; ++r) {
      rb[r][0] = Ft4[base + i + 4 + r][0];
      rb[r][1] = Ft4[base + i + 4 + r][1];
    }
#pragma unroll
    for (int r = 0; r < 4; ++r) {
      float h = w[0] * ra[r][0].x;
      h = fmaf(w[1], ra[r][0].y, h);
      h = fmaf(w[2], ra[r][0].z, h);
      h = fmaf(w[3], ra[r][0].w, h);
      h = fmaf(w[4], ra[r][1].x, h);
      h = fmaf(w[5], ra[r][1].y, h);
      mx = fmaxf(mx, h);
    }
#pragma unroll
    for (int r = 0; r < 4; ++r) {
      int nr = base + ((i + 8 + r) & 31);
      ra[r][0] = Ft4[nr][0]; ra[r][1] = Ft4[nr][1];
    }
#pragma unroll
    for (int r = 0; r < 4; ++r) {
      float h = w[0] * rb[r][0].x;
      h = fmaf(w[1], rb[r][0].y, h);
      h = fmaf(w[2], rb[r][0].z, h);
      h = fmaf(w[3], rb[r][0].w, h);
      h = fmaf(w[4], rb[r][1].x, h);
      h = fmaf(w[5], rb[r][1].y, h);
      mx = fmaxf(mx, h);
    }
  }
  smax[sub][o] = mx;
  __syncthreads();
  if (t < 64) {
    float m01 = fmaxf(smax[0][t], smax[1][t]);
    float m23 = fmaxf(smax[2][t], smax[3][t]);
    pmax[((b * 3 + kk) * 64 + t) * 32 + tile] = fmaxf(m01, m23);
  }
}

// Stable top-3 insert for the tiny tail stages.
__device__ __forceinline__ void top3_insert(float d, int m,
                                            float& d0, float& d1, float& d2,
                                            int& i0, int& i1, int& i2) {
  if (d > d2) {
    bool g1 = d > d1;
    bool g0 = d > d0;
    d2 = g1 ? d1 : d;                 i2 = g1 ? i1 : m;
    d1 = g0 ? d0 : (g1 ? d : d1);     i1 = g0 ? i0 : (g1 ? m : i1);
    d0 = g0 ? d : d0;                 i0 = g0 ? m : i0;
  }
}

// ---------------------------------------------------------------------------
// K3: per-batch tail. Reduce partials -> bn1+leaky -> x1 (64,3); graph-feature
// stages 2..4 (N=64 then 6,6; same ofs/18 decode); p[82]; MLP A/B/C; softmax.
// ---------------------------------------------------------------------------
__global__ __launch_bounds__(256) void k_tail(
    const float* __restrict__ pmax,
    const float* __restrict__ bn1g, const float* __restrict__ bn1b,
    const float* __restrict__ bn1m, const float* __restrict__ bn1v,
    const float* __restrict__ wA, const float* __restrict__ bA,
    const float* __restrict__ bnAg, const float* __restrict__ bnAb,
    const float* __restrict__ bnAm, const float* __restrict__ bnAv,
    const float* __restrict__ wB, const float* __restrict__ bB,
    const float* __restrict__ bnBg, const float* __restrict__ bnBb,
    const float* __restrict__ bnBm, const float* __restrict__ bnBv,
    const float* __restrict__ wC, const float* __restrict__ bC,
    float* __restrict__ out) {
  __shared__ float a1[192];
  __shared__ int   idx2[192];
  __shared__ float a2[18], a3[18], a4[18];
  __shared__ int   idxs[18];
  __shared__ float pv[82];
  __shared__ float hA[256];
  __shared__ float hB[128];
  __shared__ float lg[3];
  const int b = blockIdx.x;
  const int t = threadIdx.x;

  // step 1: x1[o][k] = leaky(bn1(max over 32 tiles))  (bn monotone: g>0)
  if (t < 192) {
    int o = t / 3, k = t - o * 3;
    const float4* p4 = (const float4*)(pmax + ((b * 3 + k) * 64 + o) * 32);
    float4 v[8];
#pragma unroll
    for (int j = 0; j < 8; ++j) v[j] = p4[j];
    float mx = -INFINITY;
#pragma unroll
    for (int j = 0; j < 8; ++j) {
      mx = fmaxf(mx, fmaxf(fmaxf(v[j].x, v[j].y), fmaxf(v[j].z, v[j].w)));
    }
    float inv = bn1g[o] / sqrtf(bn1v[o] + EPSV);
    float val = (mx - bn1m[o]) * inv + bn1b[o];
    a1[o * 3 + k] = val >= 0.f ? val : 0.2f * val;
  }
  __syncthreads();

  // step 2: KNN over 64 points, P_n = (a1[n], a1[64+n], a1[128+n])
  if (t < 64) {
    float px = a1[t], py = a1[64 + t], pz = a1[128 + t];
    float pp = px * px; pp = fmaf(py, py, pp); pp = fmaf(pz, pz, pp);
    float d0 = -INFINITY, d1 = -INFINITY, d2 = -INFINITY;
    int i0 = 0, i1 = 0, i2 = 0;
#pragma unroll 8
    for (int m = 0; m < 64; ++m) {
      float qx = a1[m], qy = a1[64 + m], qz = a1[128 + m];
      float qq = qx * qx; qq = fmaf(qy, qy, qq); qq = fmaf(qz, qz, qq);
      float dot = px * qx; dot = fmaf(py, qy, dot); dot = fmaf(pz, qz, dot);
      float d = 2.f * dot - pp - qq;
      top3_insert(d, m, d0, d1, d2, i0, i1, i2);
    }
    idx2[t * 3 + 0] = i0; idx2[t * 3 + 1] = i1; idx2[t * 3 + 2] = i2;
  }
  __syncthreads();

  // step 3: x2[o][kk] = max_nn F2(ofs = o*192 + kk*64 + nn)
  if (t < 18) {
    int o = t / 3, kk = t - o * 3;
    float mx = -INFINITY;
#pragma unroll 8
    for (int nn = 0; nn < 64; ++nn) {
      int ofs = o * 192 + kk * 64 + nn;
      int np = ofs / 18; int rem = ofs - np * 18;
      int kp = rem / 6;  int cp  = rem - kp * 6;
      float val = (cp < 3) ? (a1[idx2[np * 3 + kp] * 3 + cp] - a1[np * 3 + cp])
                           : a1[np * 3 + cp - 3];
      mx = fmaxf(mx, val);
    }
    a2[t] = mx;
  }
  __syncthreads();

  // steps 4-5: N=6 graph-feature twice (a2 -> a3 -> a4)
  for (int stage = 0; stage < 2; ++stage) {
    const float* src = (stage == 0) ? a2 : a3;
    float*       dst = (stage == 0) ? a3 : a4;
    if (t < 6) {
      float px = src[t], py = src[6 + t], pz = src[12 + t];
      float pp = px * px; pp = fmaf(py, py, pp); pp = fmaf(pz, pz, pp);
      float d0 = -INFINITY, d1 = -INFINITY, d2 = -INFINITY;
      int i0 = 0, i1 = 0, i2 = 0;
#pragma unroll
      for (int m = 0; m < 6; ++m) {
        float qx = src[m], qy = src[6 + m], qz = src[12 + m];
        float qq = qx * qx; qq = fmaf(qy, qy, qq); qq = fmaf(qz, qz, qq);
        float dot = px * qx; dot = fmaf(py, qy, dot); dot = fmaf(pz, qz, dot);
        float d = 2.f * dot - pp - qq;
        top3_insert(d, m, d0, d1, d2, i0, i1, i2);
      }
      idxs[t * 3 + 0] = i0; idxs[t * 3 + 1] = i1; idxs[t * 3 + 2] = i2;
    }
    __syncthreads();
    if (t < 18) {
      int o = t / 3, kk = t - o * 3;
      float mx = -INFINITY;
#pragma unroll
      for (int nn = 0; nn < 6; ++nn) {
        int ofs = o * 18 + kk * 6 + nn;
        int np = ofs / 18; int rem = ofs - np * 18;
        int kp = rem / 6;  int cp  = rem - kp * 6;
        float val = (cp < 3) ? (src[idxs[np * 3 + kp] * 3 + cp] - src[np * 3 + cp])
                             : src[np * 3 + cp - 3];
        mx = fmaxf(mx, val);
      }
      dst[t] = mx;
    }
    __syncthreads();
  }

  // step 6: p[82] = max over k
  if (t < 82) {
    float mx;
    if (t < 64)      { int o = t;      mx = fmaxf(fmaxf(a1[o*3], a1[o*3+1]), a1[o*3+2]); }
    else if (t < 70) { int o = t - 64; mx = fmaxf(fmaxf(a2[o*3], a2[o*3+1]), a2[o*3+2]); }
    else if (t < 76) { int o = t - 70; mx = fmaxf(fmaxf(a3[o*3], a3[o*3+1]), a3[o*3+2]); }
    else             { int o = t - 76; mx = fmaxf(fmaxf(a4[o*3], a4[o*3+1]), a4[o*3+2]); }
    pv[t] = mx;
  }
  __syncthreads();

  // step 7: hA = leaky(bnA(p @ wA.T + bA))  (256 outputs)
  {
    float acc = bA[t];
    const float* wr = wA + t * 82;
#pragma unroll 8
    for (int i = 0; i < 82; ++i) acc = fmaf(wr[i], pv[i], acc);
    float inv = bnAg[t] / sqrtf(bnAv[t] + EPSV);
    float v = (acc - bnAm[t]) * inv + bnAb[t];
    hA[t] = v >= 0.f ? v : 0.2f * v;
  }
  __syncthreads();

  // step 8: hB (128 outputs)
  if (t < 128) {
    float acc = bB[t];
    const float4* wr4 = (const float4*)(wB + t * 256);
#pragma unroll 8
    for (int i = 0; i < 64; ++i) {
      float4 wv = wr4[i];
      acc = fmaf(wv.x, hA[4 * i + 0], acc);
      acc = fmaf(wv.y, hA[4 * i + 1], acc);
      acc = fmaf(wv.z, hA[4 * i + 2], acc);
      acc = fmaf(wv.w, hA[4 * i + 3], acc);
    }
    float inv = bnBg[t] / sqrtf(bnBv[t] + EPSV);
    float v = (acc - bnBm[t]) * inv + bnBb[t];
    hB[t] = v >= 0.f ? v : 0.2f * v;
  }
  __syncthreads();

  // step 9: logits + softmax
  if (t < 3) {
    float acc = bC[t];
    const float* wr = wC + t * 128;
#pragma unroll 8
    for (int i = 0; i < 128; ++i) acc = fmaf(wr[i], hB[i], acc);
    lg[t] = acc;
  }
  __syncthreads();
  if (t == 0) {
    float m = fmaxf(fmaxf(lg[0], lg[1]), lg[2]);
    float e0 = expf(lg[0] - m), e1 = expf(lg[1] - m), e2 = expf(lg[2] - m);
    float s = e0 + e1 + e2;
    out[b * 3 + 0] = e0 / s;
    out[b * 3 + 1] = e1 / s;
    out[b * 3 + 2] = e2 / s;
  }
}

extern "C" void kernel_launch(void* const* d_in, const int* in_sizes, int n_in,
                              void* d_out, int out_size, void* d_ws, size_t ws_size,
                              hipStream_t stream) {
  (void)in_sizes; (void)n_in; (void)out_size; (void)ws_size;
  const float* x    = (const float*)d_in[0];
  const float* w1   = (const float*)d_in[1];
  const float* wA   = (const float*)d_in[2];
  const float* bA   = (const float*)d_in[3];
  const float* wB   = (const float*)d_in[4];
  const float* bB   = (const float*)d_in[5];
  const float* wC   = (const float*)d_in[6];
  const float* bC   = (const float*)d_in[7];
  const float* bn1g = (const float*)d_in[8];
  const float* bn1b = (const float*)d_in[9];
  const float* bn1m = (const float*)d_in[10];
  const float* bn1v = (const float*)d_in[11];
  const float* bnAg = (const float*)d_in[12];
  const float* bnAb = (const float*)d_in[13];
  const float* bnAm = (const float*)d_in[14];
  const float* bnAv = (const float*)d_in[15];
  const float* bnBg = (const float*)d_in[16];
  const float* bnBb = (const float*)d_in[17];
  const float* bnBm = (const float*)d_in[18];
  const float* bnBv = (const float*)d_in[19];
  float* out = (float*)d_out;

  int*   idx1 = (int*)d_ws;                                  // 8*4096*3 ints = 384 KB
  float* pmax = (float*)((char*)d_ws + 8 * 4096 * 3 * 4);    // 8*3*64*32 floats = 192 KB

  k_knn1<<<512, 512, 0, stream>>>(x, idx1);
  k_convmax<<<768, 256, 0, stream>>>(x, idx1, w1, pmax);
  k_tail<<<8, 256, 0, stream>>>(pmax,
                                bn1g, bn1b, bn1m, bn1v,
                                wA, bA, bnAg, bnAb, bnAm, bnAv,
                                wB, bB, bnBg, bnBb, bnBm, bnBv,
                                wC, bC, out);
}

// Round 7
// 177.792 us; speedup vs baseline: 1.0806x; 1.0004x over previous
//
#include <hip/hip_runtime.h>
#include <math.h>

#define NPTS 4096
#define EPSV 1e-5f

// 16-lane xor-butterfly max via DPP (VALU-rate, no LDS pipe).
template <int CTRL>
__device__ __forceinline__ float dpp_max(float v) {
#if __has_builtin(__builtin_amdgcn_update_dpp)
  int o = __builtin_amdgcn_update_dpp(0, __float_as_int(v), CTRL, 0xF, 0xF, true);
  return fmaxf(v, __int_as_float(o));
#else
  int lanemask = (CTRL == 0xB1) ? 1 : (CTRL == 0x4E) ? 2 : (CTRL == 0x141) ? 7 : 15;
  return fmaxf(v, __shfl_xor(v, lanemask, 16));
#endif
}

// ---------------------------------------------------------------------------
// K1: stage-1 KNN, m-in-registers two-phase (R7: forced register residency).
// Points are flat-view columns P_n = (buf[n], buf[4096+n], buf[8192+n]).
// key(q) = 2p.q - |q|^2 (per-p constant shift dropped; order-preserving).
// Thread t owns m in [8t,8t+8) as 32 NAMED scalars (R6's arrays were demoted
// to LDS -> VGPR_Count 52; named scalars make that impossible). 16-lane group
// g covers 128 m. Phase A: 24 fma + 7 max + 4 dpp-max + 1 unconditional
// ds_write (real lane -> scmax[p][g], others -> per-lane dummy; pointer picked
// once, step 32/0). theta[p] = 3rd-largest of 32 group maxes (provable lower
// bound on true 3rd key). Rescan: one ds_read_b64 (theta+32-bit group hitmask)
// per p; hit groups recompute 8 keys from regs, append to cands via LDS
// atomics. Final: exact (key desc, idx asc) top-3 = lax.top_k stable order.
// ---------------------------------------------------------------------------
__global__ __launch_bounds__(512, 4) void k_knn1(const float* __restrict__ x,
                                                 int* __restrict__ idx1) {
  __shared__ float qxs[NPTS], qys[NPTS], qzs[NPTS];   // 48 KB SoA
  __shared__ float4 ppre[64];                         // (2px,2py,2pz,0)
  __shared__ float scmax[64][32];                     // 8 KB
  __shared__ float2 thmask[65];                       // theta | hitmask (+pad)
  __shared__ int   cnt[64];
  __shared__ int   cands[64][24];
  __shared__ float dummy[512];
  const int b     = blockIdx.x >> 6;     // 64 p-ranges per batch
  const int pr    = blockIdx.x & 63;
  const int pbase = pr * 64;
  const float* xb = x + b * (NPTS * 3);
  const int t = threadIdx.x;
  const int g = t >> 4;                  // group 0..31 (128 m each)

  // ---- stage: coalesced global loads -> named regs + LDS SoA ----
  float q0x, q1x, q2x, q3x, q4x, q5x, q6x, q7x;
  float q0y, q1y, q2y, q3y, q4y, q5y, q6y, q7y;
  float q0z, q1z, q2z, q3z, q4z, q5z, q6z, q7z;
  {
    const float4* X = (const float4*)(xb + 8 * t);
    const float4* Y = (const float4*)(xb + NPTS + 8 * t);
    const float4* Z = (const float4*)(xb + 2 * NPTS + 8 * t);
    float4 x0 = X[0], x1 = X[1];
    float4 y0 = Y[0], y1 = Y[1];
    float4 z0 = Z[0], z1 = Z[1];
    q0x = x0.x; q1x = x0.y; q2x = x0.z; q3x = x0.w;
    q4x = x1.x; q5x = x1.y; q6x = x1.z; q7x = x1.w;
    q0y = y0.x; q1y = y0.y; q2y = y0.z; q3y = y0.w;
    q4y = y1.x; q5y = y1.y; q6y = y1.z; q7y = y1.w;
    q0z = z0.x; q1z = z0.y; q2z = z0.z; q3z = z0.w;
    q4z = z1.x; q5z = z1.y; q6z = z1.z; q7z = z1.w;
    *(float4*)&qxs[8 * t] = x0; *(float4*)&qxs[8 * t + 4] = x1;
    *(float4*)&qys[8 * t] = y0; *(float4*)&qys[8 * t + 4] = y1;
    *(float4*)&qzs[8 * t] = z0; *(float4*)&qzs[8 * t + 4] = z1;
  }
  const float q0w = -fmaf(q0z, q0z, fmaf(q0y, q0y, q0x * q0x));
  const float q1w = -fmaf(q1z, q1z, fmaf(q1y, q1y, q1x * q1x));
  const float q2w = -fmaf(q2z, q2z, fmaf(q2y, q2y, q2x * q2x));
  const float q3w = -fmaf(q3z, q3z, fmaf(q3y, q3y, q3x * q3x));
  const float q4w = -fmaf(q4z, q4z, fmaf(q4y, q4y, q4x * q4x));
  const float q5w = -fmaf(q5z, q5z, fmaf(q5y, q5y, q5x * q5x));
  const float q6w = -fmaf(q6z, q6z, fmaf(q6y, q6y, q6x * q6x));
  const float q7w = -fmaf(q7z, q7z, fmaf(q7y, q7y, q7x * q7x));
  if (t < 64) cnt[t] = 0;
  __syncthreads();
  if (t < 64) {
    float px = qxs[pbase + t], py = qys[pbase + t], pz = qzs[pbase + t];
    ppre[t] = make_float4(2.f * px, 2.f * py, 2.f * pz, 0.f);
  }
  __syncthreads();

  // ---- phase A: per-(p,group) max, unconditional write ----
  {
    float* wptr = ((t & 15) == 0) ? &scmax[0][g] : &dummy[t];
    const int wstep = ((t & 15) == 0) ? 32 : 0;
#pragma unroll 4
    for (int p = 0; p < 64; ++p) {
      float4 P = ppre[p];
      float k0 = fmaf(P.x, q0x, fmaf(P.y, q0y, fmaf(P.z, q0z, q0w)));
      float k1 = fmaf(P.x, q1x, fmaf(P.y, q1y, fmaf(P.z, q1z, q1w)));
      float k2 = fmaf(P.x, q2x, fmaf(P.y, q2y, fmaf(P.z, q2z, q2w)));
      float k3 = fmaf(P.x, q3x, fmaf(P.y, q3y, fmaf(P.z, q3z, q3w)));
      float k4 = fmaf(P.x, q4x, fmaf(P.y, q4y, fmaf(P.z, q4z, q4w)));
      float k5 = fmaf(P.x, q5x, fmaf(P.y, q5y, fmaf(P.z, q5z, q5w)));
      float k6 = fmaf(P.x, q6x, fmaf(P.y, q6y, fmaf(P.z, q6z, q6w)));
      float k7 = fmaf(P.x, q7x, fmaf(P.y, q7y, fmaf(P.z, q7z, q7w)));
      float v = fmaxf(fmaxf(fmaxf(k0, k1), fmaxf(k2, k3)),
                      fmaxf(fmaxf(k4, k5), fmaxf(k6, k7)));
      v = dpp_max<0xB1>(v);              // xor1
      v = dpp_max<0x4E>(v);              // xor2
      v = dpp_max<0x141>(v);             // xor7  (row_half_mirror)
      v = dpp_max<0x140>(v);             // xor15 (row_mirror)
      *wptr = v;
      wptr += wstep;
    }
  }
  __syncthreads();

  // ---- theta[p] (3rd largest of 32 group maxes) + 32-bit hit mask ----
  if (t < 64) {
    const float4* row = (const float4*)scmax[t];
    float4 r[8];
#pragma unroll
    for (int i = 0; i < 8; ++i) r[i] = row[i];
    float d0 = -INFINITY, d1 = -INFINITY, d2 = -INFINITY;
#pragma unroll
    for (int i = 0; i < 8; ++i) {
      float va[4] = {r[i].x, r[i].y, r[i].z, r[i].w};
#pragma unroll
      for (int u = 0; u < 4; ++u) {
        float v = va[u];
        float nd2 = fmaxf(d2, fminf(d1, v));
        float nd1 = fmaxf(d1, fminf(d0, v));
        d0 = fmaxf(d0, v); d1 = nd1; d2 = nd2;
      }
    }
    unsigned mask = 0;
#pragma unroll
    for (int i = 0; i < 8; ++i) {
      float va[4] = {r[i].x, r[i].y, r[i].z, r[i].w};
#pragma unroll
      for (int u = 0; u < 4; ++u)
        mask |= (va[u] >= d2) ? (1u << (4 * i + u)) : 0u;
    }
    thmask[t] = make_float2(d2, __uint_as_float(mask));
  } else if (t == 64) {
    thmask[64] = make_float2(0.f, 0.f);
  }
  __syncthreads();

  // ---- rescan: one b64 read per p; hit groups only ----
  {
    float2 tm = thmask[0];
    for (int p = 0; p < 64; ++p) {
      float2 ntm = thmask[p + 1];
      unsigned mask = __float_as_uint(tm.y);
      if ((mask >> g) & 1u) {
        float th = tm.x;
        float4 P = ppre[p];
        float kk[8];
        kk[0] = fmaf(P.x, q0x, fmaf(P.y, q0y, fmaf(P.z, q0z, q0w)));
        kk[1] = fmaf(P.x, q1x, fmaf(P.y, q1y, fmaf(P.z, q1z, q1w)));
        kk[2] = fmaf(P.x, q2x, fmaf(P.y, q2y, fmaf(P.z, q2z, q2w)));
        kk[3] = fmaf(P.x, q3x, fmaf(P.y, q3y, fmaf(P.z, q3z, q3w)));
        kk[4] = fmaf(P.x, q4x, fmaf(P.y, q4y, fmaf(P.z, q4z, q4w)));
        kk[5] = fmaf(P.x, q5x, fmaf(P.y, q5y, fmaf(P.z, q5z, q5w)));
        kk[6] = fmaf(P.x, q6x, fmaf(P.y, q6y, fmaf(P.z, q6z, q6w)));
        kk[7] = fmaf(P.x, q7x, fmaf(P.y, q7y, fmaf(P.z, q7z, q7w)));
#pragma unroll
        for (int j = 0; j < 8; ++j) {
          if (kk[j] >= th) {
            int c = atomicAdd(&cnt[p], 1);
            if (c < 24) cands[p][c] = 8 * t + j;
          }
        }
      }
      tm = ntm;
    }
  }
  __syncthreads();

  // ---- final: exact (key desc, idx asc) top-3 among candidates ----
  if (t < 64) {
    int c = cnt[t]; if (c > 24) c = 24;
    const float4 P = ppre[t];
    int* op = idx1 + (b * NPTS + pbase + t) * 3;
    float pd = INFINITY; int pi = -1;
    for (int r = 0; r < 3; ++r) {
      float bd = -INFINITY; int bi = 0x7fffffff;
      for (int cc = 0; cc < c; ++cc) {
        int m = cands[t][cc];
        float mxv = qxs[m], myv = qys[m], mzv = qzs[m];
        float mw = -fmaf(mzv, mzv, fmaf(myv, myv, mxv * mxv));
        float kv = fmaf(P.x, mxv, fmaf(P.y, myv, fmaf(P.z, mzv, mw)));
        bool allowed = (kv < pd) || (kv == pd && m > pi);
        bool better  = (kv > bd) || (kv == bd && m < bi);
        if (allowed && better) { bd = kv; bi = m; }
      }
      op[r] = bi;
      pd = bd; pi = bi;
    }
  }
}

// ---------------------------------------------------------------------------
// K2: h[b,o,k,n] = sum_c w1[o,c] * F(c,k,n), partial max over n.
// F(c,k,n): ofs = c*12288 + k*4096 + n ; n'=ofs/18, k'=(ofs%18)/6, c'=ofs%6;
//   c'<3 : x[j*3+c'] - x[n'*3+c'] with j = idx1[n'][k'] ; else x[n'*3+c'-3].
// Gathers go straight to L2. Grid 8*3*32 blocks (tile = 128 n); pmax written
// transposed: pmax[((b*3+kk)*64+o)*32 + tile].
// ---------------------------------------------------------------------------
__global__ __launch_bounds__(256) void k_convmax(const float* __restrict__ x,
                                                 const int* __restrict__ idx1,
                                                 const float* __restrict__ w1,
                                                 float* __restrict__ pmax) {
  __shared__ float4 Ft4[128][2];         // row: f0..f3 | f4,f5,--,--
  __shared__ float  w1s[384];
  __shared__ float  smax[4][64];
  const int b    = blockIdx.x / 96;      // 96 = 3*32 blocks per batch
  const int rr   = blockIdx.x - b * 96;
  const int kk   = rr >> 5;
  const int tile = rr & 31;
  const int t = threadIdx.x;
  for (int i = t; i < 384; i += 256) w1s[i] = w1[i];
  const float* xb = x + b * 12288;
  const int*   ib = idx1 + b * 12288;

  const int tn = t & 127, ch = t >> 7;   // 2 threads per n, 3 channels each
  const int n = tile * 128 + tn;
  float* ftrow = (float*)&Ft4[tn][0];
#pragma unroll
  for (int j = 0; j < 3; ++j) {
    int c = ch * 3 + j;
    int ofs = c * 12288 + kk * 4096 + n;
    int np  = ofs / 18;
    int rem = ofs - np * 18;
    int kp  = rem / 6;
    int cp  = rem - kp * 6;
    float val;
    if (cp < 3) {
      int jj = ib[np * 3 + kp];
      val = xb[jj * 3 + cp] - xb[np * 3 + cp];
    } else {
      val = xb[np * 3 + cp - 3];
    }
    ftrow[c] = val;
  }
  __syncthreads();

  const int o = t & 63, sub = t >> 6;
  float w[6];
#pragma unroll
  for (int c = 0; c < 6; ++c) w[c] = w1s[o * 6 + c];
  const int base = sub * 32;
  float mx = -INFINITY;

  float4 ra[4][2];
#pragma unroll
  for (int r = 0; r < 4; ++r) { ra[r][0] = Ft4[base + r][0]; ra[r][1] = Ft4[base + r][1]; }

  for (int i = 0; i < 32; i += 8) {
    float4 rb[4][2];
#pragma unroll
    for (int r = 0; r < 4; ++r) {
      rb[r][0] = Ft4[base + i + 4 + r][0];
      rb[r][1] = Ft4[base + i + 4 + r][1];
    }
#pragma unroll
    for (int r = 0; r < 4; ++r) {
      float h = w[0] * ra[r][0].x;
      h = fmaf(w[1], ra[r][0].y, h);
      h = fmaf(w[2], ra[r][0].z, h);
      h = fmaf(w[3], ra[r][0].w, h);
      h = fmaf(w[4], ra[r][1].x, h);
      h = fmaf(w[5], ra[r][1].y, h);
      mx = fmaxf(mx, h);
    }
#pragma unroll
    for (int r = 0; r < 4; ++r) {
      int nr = base + ((i + 8 + r) & 31);
      ra[r][0] = Ft4[nr][0]; ra[r][1] = Ft4[nr][1];
    }
#pragma unroll
    for (int r = 0; r < 4; ++r) {
      float h = w[0] * rb[r][0].x;
      h = fmaf(w[1], rb[r][0].y, h);
      h = fmaf(w[2], rb[r][0].z, h);
      h = fmaf(w[3], rb[r][0].w, h);
      h = fmaf(w[4], rb[r][1].x, h);
      h = fmaf(w[5], rb[r][1].y, h);
      mx = fmaxf(mx, h);
    }
  }
  smax[sub][o] = mx;
  __syncthreads();
  if (t < 64) {
    float m01 = fmaxf(smax[0][t], smax[1][t]);
    float m23 = fmaxf(smax[2][t], smax[3][t]);
    pmax[((b * 3 + kk) * 64 + t) * 32 + tile] = fmaxf(m01, m23);
  }
}

// Stable top-3 insert for the tiny tail stages.
__device__ __forceinline__ void top3_insert(float d, int m,
                                            float& d0, float& d1, float& d2,
                                            int& i0, int& i1, int& i2) {
  if (d > d2) {
    bool g1 = d > d1;
    bool g0 = d > d0;
    d2 = g1 ? d1 : d;                 i2 = g1 ? i1 : m;
    d1 = g0 ? d0 : (g1 ? d : d1);     i1 = g0 ? i0 : (g1 ? m : i1);
    d0 = g0 ? d : d0;                 i0 = g0 ? m : i0;
  }
}

// ---------------------------------------------------------------------------
// K3: per-batch tail. Reduce partials -> bn1+leaky -> x1 (64,3); graph-feature
// stages 2..4 (N=64 then 6,6; same ofs/18 decode); p[82]; MLP A/B/C; softmax.
// ---------------------------------------------------------------------------
__global__ __launch_bounds__(256) void k_tail(
    const float* __restrict__ pmax,
    const float* __restrict__ bn1g, const float* __restrict__ bn1b,
    const float* __restrict__ bn1m, const float* __restrict__ bn1v,
    const float* __restrict__ wA, const float* __restrict__ bA,
    const float* __restrict__ bnAg, const float* __restrict__ bnAb,
    const float* __restrict__ bnAm, const float* __restrict__ bnAv,
    const float* __restrict__ wB, const float* __restrict__ bB,
    const float* __restrict__ bnBg, const float* __restrict__ bnBb,
    const float* __restrict__ bnBm, const float* __restrict__ bnBv,
    const float* __restrict__ wC, const float* __restrict__ bC,
    float* __restrict__ out) {
  __shared__ float a1[192];
  __shared__ int   idx2[192];
  __shared__ float a2[18], a3[18], a4[18];
  __shared__ int   idxs[18];
  __shared__ float pv[82];
  __shared__ float hA[256];
  __shared__ float hB[128];
  __shared__ float lg[3];
  const int b = blockIdx.x;
  const int t = threadIdx.x;

  // step 1: x1[o][k] = leaky(bn1(max over 32 tiles))  (bn monotone: g>0)
  if (t < 192) {
    int o = t / 3, k = t - o * 3;
    const float4* p4 = (const float4*)(pmax + ((b * 3 + k) * 64 + o) * 32);
    float4 v[8];
#pragma unroll
    for (int j = 0; j < 8; ++j) v[j] = p4[j];
    float mx = -INFINITY;
#pragma unroll
    for (int j = 0; j < 8; ++j) {
      mx = fmaxf(mx, fmaxf(fmaxf(v[j].x, v[j].y), fmaxf(v[j].z, v[j].w)));
    }
    float inv = bn1g[o] / sqrtf(bn1v[o] + EPSV);
    float val = (mx - bn1m[o]) * inv + bn1b[o];
    a1[o * 3 + k] = val >= 0.f ? val : 0.2f * val;
  }
  __syncthreads();

  // step 2: KNN over 64 points, P_n = (a1[n], a1[64+n], a1[128+n])
  if (t < 64) {
    float px = a1[t], py = a1[64 + t], pz = a1[128 + t];
    float pp = px * px; pp = fmaf(py, py, pp); pp = fmaf(pz, pz, pp);
    float d0 = -INFINITY, d1 = -INFINITY, d2 = -INFINITY;
    int i0 = 0, i1 = 0, i2 = 0;
#pragma unroll 8
    for (int m = 0; m < 64; ++m) {
      float qx = a1[m], qy = a1[64 + m], qz = a1[128 + m];
      float qq = qx * qx; qq = fmaf(qy, qy, qq); qq = fmaf(qz, qz, qq);
      float dot = px * qx; dot = fmaf(py, qy, dot); dot = fmaf(pz, qz, dot);
      float d = 2.f * dot - pp - qq;
      top3_insert(d, m, d0, d1, d2, i0, i1, i2);
    }
    idx2[t * 3 + 0] = i0; idx2[t * 3 + 1] = i1; idx2[t * 3 + 2] = i2;
  }
  __syncthreads();

  // step 3: x2[o][kk] = max_nn F2(ofs = o*192 + kk*64 + nn)
  if (t < 18) {
    int o = t / 3, kk = t - o * 3;
    float mx = -INFINITY;
#pragma unroll 8
    for (int nn = 0; nn < 64; ++nn) {
      int ofs = o * 192 + kk * 64 + nn;
      int np = ofs / 18; int rem = ofs - np * 18;
      int kp = rem / 6;  int cp  = rem - kp * 6;
      float val = (cp < 3) ? (a1[idx2[np * 3 + kp] * 3 + cp] - a1[np * 3 + cp])
                           : a1[np * 3 + cp - 3];
      mx = fmaxf(mx, val);
    }
    a2[t] = mx;
  }
  __syncthreads();

  // steps 4-5: N=6 graph-feature twice (a2 -> a3 -> a4)
  for (int stage = 0; stage < 2; ++stage) {
    const float* src = (stage == 0) ? a2 : a3;
    float*       dst = (stage == 0) ? a3 : a4;
    if (t < 6) {
      float px = src[t], py = src[6 + t], pz = src[12 + t];
      float pp = px * px; pp = fmaf(py, py, pp); pp = fmaf(pz, pz, pp);
      float d0 = -INFINITY, d1 = -INFINITY, d2 = -INFINITY;
      int i0 = 0, i1 = 0, i2 = 0;
#pragma unroll
      for (int m = 0; m < 6; ++m) {
        float qx = src[m], qy = src[6 + m], qz = src[12 + m];
        float qq = qx * qx; qq = fmaf(qy, qy, qq); qq = fmaf(qz, qz, qq);
        float dot = px * qx; dot = fmaf(py, qy, dot); dot = fmaf(pz, qz, dot);
        float d = 2.f * dot - pp - qq;
        top3_insert(d, m, d0, d1, d2, i0, i1, i2);
      }
      idxs[t * 3 + 0] = i0; idxs[t * 3 + 1] = i1; idxs[t * 3 + 2] = i2;
    }
    __syncthreads();
    if (t < 18) {
      int o = t / 3, kk = t - o * 3;
      float mx = -INFINITY;
#pragma unroll
      for (int nn = 0; nn < 6; ++nn) {
        int ofs = o * 18 + kk * 6 + nn;
        int np = ofs / 18; int rem = ofs - np * 18;
        int kp = rem / 6;  int cp  = rem - kp * 6;
        float val = (cp < 3) ? (src[idxs[np * 3 + kp] * 3 + cp] - src[np * 3 + cp])
                             : src[np * 3 + cp - 3];
        mx = fmaxf(mx, val);
      }
      dst[t] = mx;
    }
    __syncthreads();
  }

  // step 6: p[82] = max over k
  if (t < 82) {
    float mx;
    if (t < 64)      { int o = t;      mx = fmaxf(fmaxf(a1[o*3], a1[o*3+1]), a1[o*3+2]); }
    else if (t < 70) { int o = t - 64; mx = fmaxf(fmaxf(a2[o*3], a2[o*3+1]), a2[o*3+2]); }
    else if (t < 76) { int o = t - 70; mx = fmaxf(fmaxf(a3[o*3], a3[o*3+1]), a3[o*3+2]); }
    else             { int o = t - 76; mx = fmaxf(fmaxf(a4[o*3], a4[o*3+1]), a4[o*3+2]); }
    pv[t] = mx;
  }
  __syncthreads();

  // step 7: hA = leaky(bnA(p @ wA.T + bA))  (256 outputs)
  {
    float acc = bA[t];
    const float* wr = wA + t * 82;
#pragma unroll 8
    for (int i = 0; i < 82; ++i) acc = fmaf(wr[i], pv[i], acc);
    float inv = bnAg[t] / sqrtf(bnAv[t] + EPSV);
    float v = (acc - bnAm[t]) * inv + bnAb[t];
    hA[t] = v >= 0.f ? v : 0.2f * v;
  }
  __syncthreads();

  // step 8: hB (128 outputs)
  if (t < 128) {
    float acc = bB[t];
    const float4* wr4 = (const float4*)(wB + t * 256);
#pragma unroll 8
    for (int i = 0; i < 64; ++i) {
      float4 wv = wr4[i];
      acc = fmaf(wv.x, hA[4 * i + 0], acc);
      acc = fmaf(wv.y, hA[4 * i + 1], acc);
      acc = fmaf(wv.z, hA[4 * i + 2], acc);
      acc = fmaf(wv.w, hA[4 * i + 3], acc);
    }
    float inv = bnBg[t] / sqrtf(bnBv[t] + EPSV);
    float v = (acc - bnBm[t]) * inv + bnBb[t];
    hB[t] = v >= 0.f ? v : 0.2f * v;
  }
  __syncthreads();

  // step 9: logits + softmax
  if (t < 3) {
    float acc = bC[t];
    const float* wr = wC + t * 128;
#pragma unroll 8
    for (int i = 0; i < 128; ++i) acc = fmaf(wr[i], hB[i], acc);
    lg[t] = acc;
  }
  __syncthreads();
  if (t == 0) {
    float m = fmaxf(fmaxf(lg[0], lg[1]), lg[2]);
    float e0 = expf(lg[0] - m), e1 = expf(lg[1] - m), e2 = expf(lg[2] - m);
    float s = e0 + e1 + e2;
    out[b * 3 + 0] = e0 / s;
    out[b * 3 + 1] = e1 / s;
    out[b * 3 + 2] = e2 / s;
  }
}

extern "C" void kernel_launch(void* const* d_in, const int* in_sizes, int n_in,
                              void* d_out, int out_size, void* d_ws, size_t ws_size,
                              hipStream_t stream) {
  (void)in_sizes; (void)n_in; (void)out_size; (void)ws_size;
  const float* x    = (const float*)d_in[0];
  const float* w1   = (const float*)d_in[1];
  const float* wA   = (const float*)d_in[2];
  const float* bA   = (const float*)d_in[3];
  const float* wB   = (const float*)d_in[4];
  const float* bB   = (const float*)d_in[5];
  const float* wC   = (const float*)d_in[6];
  const float* bC   = (const float*)d_in[7];
  const float* bn1g = (const float*)d_in[8];
  const float* bn1b = (const float*)d_in[9];
  const float* bn1m = (const float*)d_in[10];
  const float* bn1v = (const float*)d_in[11];
  const float* bnAg = (const float*)d_in[12];
  const float* bnAb = (const float*)d_in[13];
  const float* bnAm = (const float*)d_in[14];
  const float* bnAv = (const float*)d_in[15];
  const float* bnBg = (const float*)d_in[16];
  const float* bnBb = (const float*)d_in[17];
  const float* bnBm = (const float*)d_in[18];
  const float* bnBv = (const float*)d_in[19];
  float* out = (float*)d_out;

  int*   idx1 = (int*)d_ws;                                  // 8*4096*3 ints = 384 KB
  float* pmax = (float*)((char*)d_ws + 8 * 4096 * 3 * 4);    // 8*3*64*32 floats = 192 KB

  k_knn1<<<512, 512, 0, stream>>>(x, idx1);
  k_convmax<<<768, 256, 0, stream>>>(x, idx1, w1, pmax);
  k_tail<<<8, 256, 0, stream>>>(pmax,
                                bn1g, bn1b, bn1m, bn1v,
                                wA, bA, bnAg, bnAb, bnAm, bnAv,
                                wB, bB, bnBg, bnBb, bnBm, bnBv,
                                wC, bC, out);
}

// Round 8
// 177.337 us; speedup vs baseline: 1.0834x; 1.0026x over previous
//
#include <hip/hip_runtime.h>
#include <math.h>

#define NPTS 4096
#define EPSV 1e-5f

// 16-lane xor-butterfly max via DPP (VALU-rate, no LDS pipe).
template <int CTRL>
__device__ __forceinline__ float dpp_max(float v) {
#if __has_builtin(__builtin_amdgcn_update_dpp)
  int o = __builtin_amdgcn_update_dpp(0, __float_as_int(v), CTRL, 0xF, 0xF, true);
  return fmaxf(v, __int_as_float(o));
#else
  int lanemask = (CTRL == 0xB1) ? 1 : (CTRL == 0x4E) ? 2 : (CTRL == 0x141) ? 7 : 15;
  return fmaxf(v, __shfl_xor(v, lanemask, 16));
#endif
}

// ---------------------------------------------------------------------------
// K1: stage-1 KNN, m-in-registers two-phase (R8: NO LDS copy of q -- R6/R7's
// VGPR=52 showed the compiler rematerialized q from the LDS SoA copy instead
// of keeping registers; removing the copy makes that impossible).
// Points are flat-view columns P_n = (buf[n], buf[4096+n], buf[8192+n]).
// key(q) = 2p.q - |q|^2 (per-p constant shift dropped; order-preserving).
// Thread t owns m in [8t,8t+8) as 32 named scalars. 16-lane group g covers
// 128 m. Phase A: 24 fma + 7 max + 4 dpp-max + 1 unconditional ds_write per p.
// theta[p] = 3rd-largest of 32 group maxes (lower bound on true 3rd key).
// Rescan: ds_read_b64 (theta|hitmask) per p; hit groups recompute keys from
// regs and append (key,m) to cand lists. Final: exact (key desc, idx asc)
// top-3 over stored candidate keys = lax.top_k stable order.
// ---------------------------------------------------------------------------
__global__ __launch_bounds__(512, 4) void k_knn1(const float* __restrict__ x,
                                                 int* __restrict__ idx1) {
  __shared__ float4 ppre[64];            // (2px,2py,2pz,0)
  __shared__ float  scmax[64][32];       // 8 KB
  __shared__ float2 thmask[65];          // theta | hitmask (+pad)
  __shared__ int    cnt[64];
  __shared__ float  candk[64][24];       // 6 KB
  __shared__ int    candi[64][24];       // 6 KB
  __shared__ float  dummy[512];
  const int b     = blockIdx.x >> 6;     // 64 p-ranges per batch
  const int pr    = blockIdx.x & 63;
  const int pbase = pr * 64;
  const float* xb = x + b * (NPTS * 3);
  const int t = threadIdx.x;
  const int g = t >> 4;                  // group 0..31 (128 m each)

  // ---- stage: coalesced global loads -> named regs ONLY ----
  float q0x, q1x, q2x, q3x, q4x, q5x, q6x, q7x;
  float q0y, q1y, q2y, q3y, q4y, q5y, q6y, q7y;
  float q0z, q1z, q2z, q3z, q4z, q5z, q6z, q7z;
  {
    const float4* X = (const float4*)(xb + 8 * t);
    const float4* Y = (const float4*)(xb + NPTS + 8 * t);
    const float4* Z = (const float4*)(xb + 2 * NPTS + 8 * t);
    float4 x0 = X[0], x1 = X[1];
    float4 y0 = Y[0], y1 = Y[1];
    float4 z0 = Z[0], z1 = Z[1];
    q0x = x0.x; q1x = x0.y; q2x = x0.z; q3x = x0.w;
    q4x = x1.x; q5x = x1.y; q6x = x1.z; q7x = x1.w;
    q0y = y0.x; q1y = y0.y; q2y = y0.z; q3y = y0.w;
    q4y = y1.x; q5y = y1.y; q6y = y1.z; q7y = y1.w;
    q0z = z0.x; q1z = z0.y; q2z = z0.z; q3z = z0.w;
    q4z = z1.x; q5z = z1.y; q6z = z1.z; q7z = z1.w;
  }
  const float q0w = -fmaf(q0z, q0z, fmaf(q0y, q0y, q0x * q0x));
  const float q1w = -fmaf(q1z, q1z, fmaf(q1y, q1y, q1x * q1x));
  const float q2w = -fmaf(q2z, q2z, fmaf(q2y, q2y, q2x * q2x));
  const float q3w = -fmaf(q3z, q3z, fmaf(q3y, q3y, q3x * q3x));
  const float q4w = -fmaf(q4z, q4z, fmaf(q4y, q4y, q4x * q4x));
  const float q5w = -fmaf(q5z, q5z, fmaf(q5y, q5y, q5x * q5x));
  const float q6w = -fmaf(q6z, q6z, fmaf(q6y, q6y, q6x * q6x));
  const float q7w = -fmaf(q7z, q7z, fmaf(q7y, q7y, q7x * q7x));
  if (t < 64) {
    float px = xb[pbase + t];
    float py = xb[NPTS + pbase + t];
    float pz = xb[2 * NPTS + pbase + t];
    ppre[t] = make_float4(2.f * px, 2.f * py, 2.f * pz, 0.f);
    cnt[t] = 0;
  }
  __syncthreads();

  // ---- phase A: per-(p,group) max, unconditional write ----
  {
    float* wptr = ((t & 15) == 0) ? &scmax[0][g] : &dummy[t];
    const int wstep = ((t & 15) == 0) ? 32 : 0;
#pragma unroll 4
    for (int p = 0; p < 64; ++p) {
      float4 P = ppre[p];
      float k0 = fmaf(P.x, q0x, fmaf(P.y, q0y, fmaf(P.z, q0z, q0w)));
      float k1 = fmaf(P.x, q1x, fmaf(P.y, q1y, fmaf(P.z, q1z, q1w)));
      float k2 = fmaf(P.x, q2x, fmaf(P.y, q2y, fmaf(P.z, q2z, q2w)));
      float k3 = fmaf(P.x, q3x, fmaf(P.y, q3y, fmaf(P.z, q3z, q3w)));
      float k4 = fmaf(P.x, q4x, fmaf(P.y, q4y, fmaf(P.z, q4z, q4w)));
      float k5 = fmaf(P.x, q5x, fmaf(P.y, q5y, fmaf(P.z, q5z, q5w)));
      float k6 = fmaf(P.x, q6x, fmaf(P.y, q6y, fmaf(P.z, q6z, q6w)));
      float k7 = fmaf(P.x, q7x, fmaf(P.y, q7y, fmaf(P.z, q7z, q7w)));
      float v = fmaxf(fmaxf(fmaxf(k0, k1), fmaxf(k2, k3)),
                      fmaxf(fmaxf(k4, k5), fmaxf(k6, k7)));
      v = dpp_max<0xB1>(v);              // xor1
      v = dpp_max<0x4E>(v);              // xor2
      v = dpp_max<0x141>(v);             // xor7  (row_half_mirror)
      v = dpp_max<0x140>(v);             // xor15 (row_mirror)
      *wptr = v;
      wptr += wstep;
    }
  }
  __syncthreads();

  // ---- theta[p] (3rd largest of 32 group maxes) + 32-bit hit mask ----
  if (t < 64) {
    const float4* row = (const float4*)scmax[t];
    float4 r[8];
#pragma unroll
    for (int i = 0; i < 8; ++i) r[i] = row[i];
    float d0 = -INFINITY, d1 = -INFINITY, d2 = -INFINITY;
#pragma unroll
    for (int i = 0; i < 8; ++i) {
      float va[4] = {r[i].x, r[i].y, r[i].z, r[i].w};
#pragma unroll
      for (int u = 0; u < 4; ++u) {
        float v = va[u];
        float nd2 = fmaxf(d2, fminf(d1, v));
        float nd1 = fmaxf(d1, fminf(d0, v));
        d0 = fmaxf(d0, v); d1 = nd1; d2 = nd2;
      }
    }
    unsigned mask = 0;
#pragma unroll
    for (int i = 0; i < 8; ++i) {
      float va[4] = {r[i].x, r[i].y, r[i].z, r[i].w};
#pragma unroll
      for (int u = 0; u < 4; ++u)
        mask |= (va[u] >= d2) ? (1u << (4 * i + u)) : 0u;
    }
    thmask[t] = make_float2(d2, __uint_as_float(mask));
  } else if (t == 64) {
    thmask[64] = make_float2(0.f, 0.f);
  }
  __syncthreads();

  // ---- rescan: one b64 read per p; hit groups recompute keys from regs ----
  {
    float2 tm = thmask[0];
    for (int p = 0; p < 64; ++p) {
      float2 ntm = thmask[p + 1];
      unsigned mask = __float_as_uint(tm.y);
      if ((mask >> g) & 1u) {
        float th = tm.x;
        float4 P = ppre[p];
        float kk[8];
        kk[0] = fmaf(P.x, q0x, fmaf(P.y, q0y, fmaf(P.z, q0z, q0w)));
        kk[1] = fmaf(P.x, q1x, fmaf(P.y, q1y, fmaf(P.z, q1z, q1w)));
        kk[2] = fmaf(P.x, q2x, fmaf(P.y, q2y, fmaf(P.z, q2z, q2w)));
        kk[3] = fmaf(P.x, q3x, fmaf(P.y, q3y, fmaf(P.z, q3z, q3w)));
        kk[4] = fmaf(P.x, q4x, fmaf(P.y, q4y, fmaf(P.z, q4z, q4w)));
        kk[5] = fmaf(P.x, q5x, fmaf(P.y, q5y, fmaf(P.z, q5z, q5w)));
        kk[6] = fmaf(P.x, q6x, fmaf(P.y, q6y, fmaf(P.z, q6z, q6w)));
        kk[7] = fmaf(P.x, q7x, fmaf(P.y, q7y, fmaf(P.z, q7z, q7w)));
#pragma unroll
        for (int j = 0; j < 8; ++j) {
          if (kk[j] >= th) {
            int c = atomicAdd(&cnt[p], 1);
            if (c < 24) { candk[p][c] = kk[j]; candi[p][c] = 8 * t + j; }
          }
        }
      }
      tm = ntm;
    }
  }
  __syncthreads();

  // ---- final: exact (key desc, idx asc) top-3 among stored candidates ----
  if (t < 64) {
    int c = cnt[t]; if (c > 24) c = 24;
    int* op = idx1 + (b * NPTS + pbase + t) * 3;
    float pd = INFINITY; int pi = -1;
    for (int r = 0; r < 3; ++r) {
      float bd = -INFINITY; int bi = 0x7fffffff;
      for (int cc = 0; cc < c; ++cc) {
        float kv = candk[t][cc];
        int m = candi[t][cc];
        bool allowed = (kv < pd) || (kv == pd && m > pi);
        bool better  = (kv > bd) || (kv == bd && m < bi);
        if (allowed && better) { bd = kv; bi = m; }
      }
      op[r] = bi;
      pd = bd; pi = bi;
    }
  }
}

// ---------------------------------------------------------------------------
// K2: h[b,o,k,n] = sum_c w1[o,c] * F(c,k,n), partial max over n.
// F(c,k,n): ofs = c*12288 + k*4096 + n ; n'=ofs/18, k'=(ofs%18)/6, c'=ofs%6;
//   c'<3 : x[j*3+c'] - x[n'*3+c'] with j = idx1[n'][k'] ; else x[n'*3+c'-3].
// Gathers go straight to L2. Grid 8*3*32 blocks (tile = 128 n); pmax written
// transposed: pmax[((b*3+kk)*64+o)*32 + tile].
// ---------------------------------------------------------------------------
__global__ __launch_bounds__(256) void k_convmax(const float* __restrict__ x,
                                                 const int* __restrict__ idx1,
                                                 const float* __restrict__ w1,
                                                 float* __restrict__ pmax) {
  __shared__ float4 Ft4[128][2];         // row: f0..f3 | f4,f5,--,--
  __shared__ float  w1s[384];
  __shared__ float  smax[4][64];
  const int b    = blockIdx.x / 96;      // 96 = 3*32 blocks per batch
  const int rr   = blockIdx.x - b * 96;
  const int kk   = rr >> 5;
  const int tile = rr & 31;
  const int t = threadIdx.x;
  for (int i = t; i < 384; i += 256) w1s[i] = w1[i];
  const float* xb = x + b * 12288;
  const int*   ib = idx1 + b * 12288;

  const int tn = t & 127, ch = t >> 7;   // 2 threads per n, 3 channels each
  const int n = tile * 128 + tn;
  float* ftrow = (float*)&Ft4[tn][0];
#pragma unroll
  for (int j = 0; j < 3; ++j) {
    int c = ch * 3 + j;
    int ofs = c * 12288 + kk * 4096 + n;
    int np  = ofs / 18;
    int rem = ofs - np * 18;
    int kp  = rem / 6;
    int cp  = rem - kp * 6;
    float val;
    if (cp < 3) {
      int jj = ib[np * 3 + kp];
      val = xb[jj * 3 + cp] - xb[np * 3 + cp];
    } else {
      val = xb[np * 3 + cp - 3];
    }
    ftrow[c] = val;
  }
  __syncthreads();

  const int o = t & 63, sub = t >> 6;
  float w[6];
#pragma unroll
  for (int c = 0; c < 6; ++c) w[c] = w1s[o * 6 + c];
  const int base = sub * 32;
  float mx = -INFINITY;

  float4 ra[4][2];
#pragma unroll
  for (int r = 0; r < 4; ++r) { ra[r][0] = Ft4[base + r][0]; ra[r][1] = Ft4[base + r][1]; }

  for (int i = 0; i < 32; i += 8) {
    float4 rb[4][2];
#pragma unroll
    for (int r = 0; r < 4; ++r) {
      rb[r][0] = Ft4[base + i + 4 + r][0];
      rb[r][1] = Ft4[base + i + 4 + r][1];
    }
#pragma unroll
    for (int r = 0; r < 4; ++r) {
      float h = w[0] * ra[r][0].x;
      h = fmaf(w[1], ra[r][0].y, h);
      h = fmaf(w[2], ra[r][0].z, h);
      h = fmaf(w[3], ra[r][0].w, h);
      h = fmaf(w[4], ra[r][1].x, h);
      h = fmaf(w[5], ra[r][1].y, h);
      mx = fmaxf(mx, h);
    }
#pragma unroll
    for (int r = 0; r < 4; ++r) {
      int nr = base + ((i + 8 + r) & 31);
      ra[r][0] = Ft4[nr][0]; ra[r][1] = Ft4[nr][1];
    }
#pragma unroll
    for (int r = 0; r < 4; ++r) {
      float h = w[0] * rb[r][0].x;
      h = fmaf(w[1], rb[r][0].y, h);
      h = fmaf(w[2], rb[r][0].z, h);
      h = fmaf(w[3], rb[r][0].w, h);
      h = fmaf(w[4], rb[r][1].x, h);
      h = fmaf(w[5], rb[r][1].y, h);
      mx = fmaxf(mx, h);
    }
  }
  smax[sub][o] = mx;
  __syncthreads();
  if (t < 64) {
    float m01 = fmaxf(smax[0][t], smax[1][t]);
    float m23 = fmaxf(smax[2][t], smax[3][t]);
    pmax[((b * 3 + kk) * 64 + t) * 32 + tile] = fmaxf(m01, m23);
  }
}

// Stable top-3 insert for the tiny tail stages.
__device__ __forceinline__ void top3_insert(float d, int m,
                                            float& d0, float& d1, float& d2,
                                            int& i0, int& i1, int& i2) {
  if (d > d2) {
    bool g1 = d > d1;
    bool g0 = d > d0;
    d2 = g1 ? d1 : d;                 i2 = g1 ? i1 : m;
    d1 = g0 ? d0 : (g1 ? d : d1);     i1 = g0 ? i0 : (g1 ? m : i1);
    d0 = g0 ? d : d0;                 i0 = g0 ? m : i0;
  }
}

// ---------------------------------------------------------------------------
// K3: per-batch tail. Reduce partials -> bn1+leaky -> x1 (64,3); graph-feature
// stages 2..4 (N=64 then 6,6; same ofs/18 decode); p[82]; MLP A/B/C; softmax.
// ---------------------------------------------------------------------------
__global__ __launch_bounds__(256) void k_tail(
    const float* __restrict__ pmax,
    const float* __restrict__ bn1g, const float* __restrict__ bn1b,
    const float* __restrict__ bn1m, const float* __restrict__ bn1v,
    const float* __restrict__ wA, const float* __restrict__ bA,
    const float* __restrict__ bnAg, const float* __restrict__ bnAb,
    const float* __restrict__ bnAm, const float* __restrict__ bnAv,
    const float* __restrict__ wB, const float* __restrict__ bB,
    const float* __restrict__ bnBg, const float* __restrict__ bnBb,
    const float* __restrict__ bnBm, const float* __restrict__ bnBv,
    const float* __restrict__ wC, const float* __restrict__ bC,
    float* __restrict__ out) {
  __shared__ float a1[192];
  __shared__ int   idx2[192];
  __shared__ float a2[18], a3[18], a4[18];
  __shared__ int   idxs[18];
  __shared__ float pv[82];
  __shared__ float hA[256];
  __shared__ float hB[128];
  __shared__ float lg[3];
  const int b = blockIdx.x;
  const int t = threadIdx.x;

  // step 1: x1[o][k] = leaky(bn1(max over 32 tiles))  (bn monotone: g>0)
  if (t < 192) {
    int o = t / 3, k = t - o * 3;
    const float4* p4 = (const float4*)(pmax + ((b * 3 + k) * 64 + o) * 32);
    float4 v[8];
#pragma unroll
    for (int j = 0; j < 8; ++j) v[j] = p4[j];
    float mx = -INFINITY;
#pragma unroll
    for (int j = 0; j < 8; ++j) {
      mx = fmaxf(mx, fmaxf(fmaxf(v[j].x, v[j].y), fmaxf(v[j].z, v[j].w)));
    }
    float inv = bn1g[o] / sqrtf(bn1v[o] + EPSV);
    float val = (mx - bn1m[o]) * inv + bn1b[o];
    a1[o * 3 + k] = val >= 0.f ? val : 0.2f * val;
  }
  __syncthreads();

  // step 2: KNN over 64 points, P_n = (a1[n], a1[64+n], a1[128+n])
  if (t < 64) {
    float px = a1[t], py = a1[64 + t], pz = a1[128 + t];
    float pp = px * px; pp = fmaf(py, py, pp); pp = fmaf(pz, pz, pp);
    float d0 = -INFINITY, d1 = -INFINITY, d2 = -INFINITY;
    int i0 = 0, i1 = 0, i2 = 0;
#pragma unroll 8
    for (int m = 0; m < 64; ++m) {
      float qx = a1[m], qy = a1[64 + m], qz = a1[128 + m];
      float qq = qx * qx; qq = fmaf(qy, qy, qq); qq = fmaf(qz, qz, qq);
      float dot = px * qx; dot = fmaf(py, qy, dot); dot = fmaf(pz, qz, dot);
      float d = 2.f * dot - pp - qq;
      top3_insert(d, m, d0, d1, d2, i0, i1, i2);
    }
    idx2[t * 3 + 0] = i0; idx2[t * 3 + 1] = i1; idx2[t * 3 + 2] = i2;
  }
  __syncthreads();

  // step 3: x2[o][kk] = max_nn F2(ofs = o*192 + kk*64 + nn)
  if (t < 18) {
    int o = t / 3, kk = t - o * 3;
    float mx = -INFINITY;
#pragma unroll 8
    for (int nn = 0; nn < 64; ++nn) {
      int ofs = o * 192 + kk * 64 + nn;
      int np = ofs / 18; int rem = ofs - np * 18;
      int kp = rem / 6;  int cp  = rem - kp * 6;
      float val = (cp < 3) ? (a1[idx2[np * 3 + kp] * 3 + cp] - a1[np * 3 + cp])
                           : a1[np * 3 + cp - 3];
      mx = fmaxf(mx, val);
    }
    a2[t] = mx;
  }
  __syncthreads();

  // steps 4-5: N=6 graph-feature twice (a2 -> a3 -> a4)
  for (int stage = 0; stage < 2; ++stage) {
    const float* src = (stage == 0) ? a2 : a3;
    float*       dst = (stage == 0) ? a3 : a4;
    if (t < 6) {
      float px = src[t], py = src[6 + t], pz = src[12 + t];
      float pp = px * px; pp = fmaf(py, py, pp); pp = fmaf(pz, pz, pp);
      float d0 = -INFINITY, d1 = -INFINITY, d2 = -INFINITY;
      int i0 = 0, i1 = 0, i2 = 0;
#pragma unroll
      for (int m = 0; m < 6; ++m) {
        float qx = src[m], qy = src[6 + m], qz = src[12 + m];
        float qq = qx * qx; qq = fmaf(qy, qy, qq); qq = fmaf(qz, qz, qq);
        float dot = px * qx; dot = fmaf(py, qy, dot); dot = fmaf(pz, qz, dot);
        float d = 2.f * dot - pp - qq;
        top3_insert(d, m, d0, d1, d2, i0, i1, i2);
      }
      idxs[t * 3 + 0] = i0; idxs[t * 3 + 1] = i1; idxs[t * 3 + 2] = i2;
    }
    __syncthreads();
    if (t < 18) {
      int o = t / 3, kk = t - o * 3;
      float mx = -INFINITY;
#pragma unroll
      for (int nn = 0; nn < 6; ++nn) {
        int ofs = o * 18 + kk * 6 + nn;
        int np = ofs / 18; int rem = ofs - np * 18;
        int kp = rem / 6;  int cp  = rem - kp * 6;
        float val = (cp < 3) ? (src[idxs[np * 3 + kp] * 3 + cp] - src[np * 3 + cp])
                             : src[np * 3 + cp - 3];
        mx = fmaxf(mx, val);
      }
      dst[t] = mx;
    }
    __syncthreads();
  }

  // step 6: p[82] = max over k
  if (t < 82) {
    float mx;
    if (t < 64)      { int o = t;      mx = fmaxf(fmaxf(a1[o*3], a1[o*3+1]), a1[o*3+2]); }
    else if (t < 70) { int o = t - 64; mx = fmaxf(fmaxf(a2[o*3], a2[o*3+1]), a2[o*3+2]); }
    else if (t < 76) { int o = t - 70; mx = fmaxf(fmaxf(a3[o*3], a3[o*3+1]), a3[o*3+2]); }
    else             { int o = t - 76; mx = fmaxf(fmaxf(a4[o*3], a4[o*3+1]), a4[o*3+2]); }
    pv[t] = mx;
  }
  __syncthreads();

  // step 7: hA = leaky(bnA(p @ wA.T + bA))  (256 outputs)
  {
    float acc = bA[t];
    const float* wr = wA + t * 82;
#pragma unroll 8
    for (int i = 0; i < 82; ++i) acc = fmaf(wr[i], pv[i], acc);
    float inv = bnAg[t] / sqrtf(bnAv[t] + EPSV);
    float v = (acc - bnAm[t]) * inv + bnAb[t];
    hA[t] = v >= 0.f ? v : 0.2f * v;
  }
  __syncthreads();

  // step 8: hB (128 outputs)
  if (t < 128) {
    float acc = bB[t];
    const float4* wr4 = (const float4*)(wB + t * 256);
#pragma unroll 8
    for (int i = 0; i < 64; ++i) {
      float4 wv = wr4[i];
      acc = fmaf(wv.x, hA[4 * i + 0], acc);
      acc = fmaf(wv.y, hA[4 * i + 1], acc);
      acc = fmaf(wv.z, hA[4 * i + 2], acc);
      acc = fmaf(wv.w, hA[4 * i + 3], acc);
    }
    float inv = bnBg[t] / sqrtf(bnBv[t] + EPSV);
    float v = (acc - bnBm[t]) * inv + bnBb[t];
    hB[t] = v >= 0.f ? v : 0.2f * v;
  }
  __syncthreads();

  // step 9: logits + softmax
  if (t < 3) {
    float acc = bC[t];
    const float* wr = wC + t * 128;
#pragma unroll 8
    for (int i = 0; i < 128; ++i) acc = fmaf(wr[i], hB[i], acc);
    lg[t] = acc;
  }
  __syncthreads();
  if (t == 0) {
    float m = fmaxf(fmaxf(lg[0], lg[1]), lg[2]);
    float e0 = expf(lg[0] - m), e1 = expf(lg[1] - m), e2 = expf(lg[2] - m);
    float s = e0 + e1 + e2;
    out[b * 3 + 0] = e0 / s;
    out[b * 3 + 1] = e1 / s;
    out[b * 3 + 2] = e2 / s;
  }
}

extern "C" void kernel_launch(void* const* d_in, const int* in_sizes, int n_in,
                              void* d_out, int out_size, void* d_ws, size_t ws_size,
                              hipStream_t stream) {
  (void)in_sizes; (void)n_in; (void)out_size; (void)ws_size;
  const float* x    = (const float*)d_in[0];
  const float* w1   = (const float*)d_in[1];
  const float* wA   = (const float*)d_in[2];
  const float* bA   = (const float*)d_in[3];
  const float* wB   = (const float*)d_in[4];
  const float* bB   = (const float*)d_in[5];
  const float* wC   = (const float*)d_in[6];
  const float* bC   = (const float*)d_in[7];
  const float* bn1g = (const float*)d_in[8];
  const float* bn1b = (const float*)d_in[9];
  const float* bn1m = (const float*)d_in[10];
  const float* bn1v = (const float*)d_in[11];
  const float* bnAg = (const float*)d_in[12];
  const float* bnAb = (const float*)d_in[13];
  const float* bnAm = (const float*)d_in[14];
  const float* bnAv = (const float*)d_in[15];
  const float* bnBg = (const float*)d_in[16];
  const float* bnBb = (const float*)d_in[17];
  const float* bnBm = (const float*)d_in[18];
  const float* bnBv = (const float*)d_in[19];
  float* out = (float*)d_out;

  int*   idx1 = (int*)d_ws;                                  // 8*4096*3 ints = 384 KB
  float* pmax = (float*)((char*)d_ws + 8 * 4096 * 3 * 4);    // 8*3*64*32 floats = 192 KB

  k_knn1<<<512, 512, 0, stream>>>(x, idx1);
  k_convmax<<<768, 256, 0, stream>>>(x, idx1, w1, pmax);
  k_tail<<<8, 256, 0, stream>>>(pmax,
                                bn1g, bn1b, bn1m, bn1v,
                                wA, bA, bnAg, bnAb, bnAm, bnAv,
                                wB, bB, bnBg, bnBb, bnBm, bnBv,
                                wC, bC, out);
}